// Round 11
// baseline (79.182 us; speedup 1.0000x reference)
//
#include <hip/hip_runtime.h>

#define B 32
#define M 32
#define H 128
#define EPS 1e-6f
#define TSCALE 2.8853900817779268f   // 2*log2(e)

// ---------------- workspace layout (floats) ----------------
// metric @ 0      : 32768
// mj     @ 32768  : 262144   mj[b][j][d] = metric[b,j,:] @ Wr1[64:96]
// S      @ 294912 : 8192
// bc1s   @ 303104 : 128      bc1 * 2log2(e)
// Kc     @ 303232 : 1        sum(Wc2) + bc2
// cnt    @ 303236 : 32 ints
// Wp     @ 303268 : 262144   Wp[u][b][i] = sum_j sym(Wr2)[u,i,j] * p[b,j]
// c2     @ 565412 : 1024     c2[b][i]    = sum_j sym(br2)[i,j] * p[b,j]

#define FMA4(P, s, W) \
    P.x = fmaf((s), (W).x, P.x); P.y = fmaf((s), (W).y, P.y); \
    P.z = fmaf((s), (W).z, P.z); P.w = fmaf((s), (W).w, P.w);

// Kernel 1, grid 289: blocks 0-31 = per-b prep (metric, mj, zero S/cnt,
// chris constants); blocks 32-287 = Wp row u = blk-32; block 288 = c2.
__global__ __launch_bounds__(256) void k_prep(
    const float* __restrict__ points, const float* __restrict__ Wm1,
    const float* __restrict__ bm1, const float* __restrict__ Wm2,
    const float* __restrict__ bm2, const float* __restrict__ Wr1,
    const float* __restrict__ bc1, const float* __restrict__ Wc2,
    const float* __restrict__ bc2, const float* __restrict__ Wr2,
    const float* __restrict__ br2,
    float* __restrict__ metric, float* __restrict__ mj,
    float* __restrict__ S, float* __restrict__ bc1s, float* __restrict__ Kc,
    int* __restrict__ cnt, float* __restrict__ Wp, float* __restrict__ c2)
{
    __shared__ float sbuf[3072];
    const int role = blockIdx.x, t = threadIdx.x;

    if (role >= B) {
        // ---- Wp / c2 path: symmetrize one Wr2 row, contract with points ----
        const int u = role - B;                 // 0..255 = Wr2 row, 256 = br2
        float* row    = sbuf;                   // 1024
        float* rowsym = sbuf + 1024;            // 1024
        float* ps     = sbuf + 2048;            // 1024 (all B*M points)
        const float* src = (u < 256) ? (Wr2 + u * 1024) : br2;
        #pragma unroll
        for (int r = 0; r < 4; ++r) {
            row[t + 256 * r] = src[t + 256 * r];
            ps[t + 256 * r]  = points[t + 256 * r];
        }
        __syncthreads();
        #pragma unroll
        for (int r = 0; r < 4; ++r) {
            const int d = t + 256 * r, ii = d >> 5, jj = d & 31;
            rowsym[d] = 0.5f * (row[d] + row[jj * 32 + ii]);
        }
        __syncthreads();
        const int b = t >> 3, i0 = (t & 7) * 4;
        const float4* rs4 = (const float4*)rowsym;
        const float4* p4  = (const float4*)(ps + b * 32);
        float4 o; o.x = o.y = o.z = o.w = 0.f;
        #pragma unroll
        for (int m = 0; m < 8; ++m) {
            const float4 pv = p4[m];
            const float4 r0 = rs4[(i0 + 0) * 8 + m];
            const float4 r1 = rs4[(i0 + 1) * 8 + m];
            const float4 r2 = rs4[(i0 + 2) * 8 + m];
            const float4 r3 = rs4[(i0 + 3) * 8 + m];
            o.x = fmaf(pv.x, r0.x, fmaf(pv.y, r0.y, fmaf(pv.z, r0.z, fmaf(pv.w, r0.w, o.x))));
            o.y = fmaf(pv.x, r1.x, fmaf(pv.y, r1.y, fmaf(pv.z, r1.z, fmaf(pv.w, r1.w, o.y))));
            o.z = fmaf(pv.x, r2.x, fmaf(pv.y, r2.y, fmaf(pv.z, r2.z, fmaf(pv.w, r2.w, o.z))));
            o.w = fmaf(pv.x, r3.x, fmaf(pv.y, r3.y, fmaf(pv.z, r3.z, fmaf(pv.w, r3.w, o.w))));
        }
        if (u < 256) ((float4*)(Wp + u * 1024 + b * 32))[t & 7] = o;
        else         ((float4*)(c2 + b * 32))[t & 7] = o;
        return;
    }

    // ---- per-b prep path ----
    const int b = role;
    float* p     = sbuf;           // 32
    float* h     = sbuf + 32;      // 128
    float* comps = sbuf + 160;     // 1024
    float* msym  = sbuf + 1184;    // 1024
    if (t < M) p[t] = points[b * M + t];
    __syncthreads();
    if (t < H) {
        float acc = bm1[t];
        #pragma unroll
        for (int m = 0; m < M; ++m) acc = fmaf(p[m], Wm1[m * H + t], acc);
        h[t] = fmaxf(acc, 0.f);
    }
    __syncthreads();
    #pragma unroll
    for (int r = 0; r < 4; ++r) {
        const int d = t + 256 * r;
        float acc = bm2[d];
        for (int u = 0; u < H; ++u) acc = fmaf(h[u], Wm2[u * (M * M) + d], acc);
        comps[d] = acc;
    }
    __syncthreads();
    #pragma unroll
    for (int r = 0; r < 4; ++r) {
        const int d = t + 256 * r;
        const int ii = d >> 5, jj = d & 31;
        float v = 0.5f * (comps[ii * M + jj] + comps[jj * M + ii]) + (ii == jj ? EPS : 0.f);
        metric[b * M * M + d] = v;
        msym[d] = v;
    }
    S[b * 256 + t] = 0.f;
    if (t == 0) cnt[b] = 0;
    __syncthreads();
    float wreg[M];
    #pragma unroll
    for (int m = 0; m < M; ++m) wreg[m] = Wr1[(64 + m) * 256 + t];
    const float4* msym4 = (const float4*)msym;
    for (int x = 0; x < M; ++x) {
        float acc = 0.f;
        #pragma unroll
        for (int mq = 0; mq < 8; ++mq) {
            float4 mv = msym4[x * 8 + mq];
            acc = fmaf(mv.x, wreg[4 * mq + 0], acc);
            acc = fmaf(mv.y, wreg[4 * mq + 1], acc);
            acc = fmaf(mv.z, wreg[4 * mq + 2], acc);
            acc = fmaf(mv.w, wreg[4 * mq + 3], acc);
        }
        mj[(b * M + x) * 256 + t] = acc;
    }
    if (b == 0) {
        if (t < H) bc1s[t] = bc1[t] * TSCALE;
        if (t == 0) {
            float s = bc2[0];
            for (int u = 0; u < H; ++u) s += Wc2[u];
            Kc[0] = s;
        }
    }
}

// Kernel 2: per block (b,i): christoffel MLP + ricci layer-1 + reduce into
// S[b]; the 32nd finishing block per b runs the tiny Wp-based epilogue.
// 512 threads = 8 waves. LDS ~39 KB -> 4 blocks/CU.
// (512,6): (512,8) forced a 64-VGPR cap and spilled (round-4 regression).
// NOTE: no barrier between chris write and ricci read — wave w writes and
// reads only mc[w*128 .. w*128+127]; intra-wave lgkmcnt ordering suffices.
// This lets waves skew so trans-heavy chris overlaps LDS-heavy ricci.
__global__ __launch_bounds__(512, 6) void k_main(
    const float* __restrict__ points, const float* __restrict__ metric,
    const float* __restrict__ mj, const float* __restrict__ Wc1,
    const float* __restrict__ Wc2, const float* __restrict__ bc1s,
    const float* __restrict__ Kc, const float* __restrict__ Wr1,
    const float* __restrict__ br1, float* __restrict__ S,
    int* __restrict__ cnt,
    const float* __restrict__ Wp, const float* __restrict__ c2,
    const float* __restrict__ Wf1, const float* __restrict__ bf1,
    const float* __restrict__ Wf2, const float* __restrict__ bf2,
    const float* __restrict__ Wh1, const float* __restrict__ bh1,
    const float* __restrict__ Wh2, const float* __restrict__ bh2,
    float* __restrict__ out)
{
    const int blk = blockIdx.x;
    const int b = blk >> 5, i = blk & 31;
    const int t = threadIdx.x;

    __shared__ float wr1c[M * 256];   // Wr1[96:128] — 32 KB (epilogue scratch later)
    __shared__ float mc[M * M];       // metric[b] first, per-wave chris scratch after
    __shared__ float bmi[256];
    __shared__ float Slds[256];
    __shared__ int finflag;

    {
        const float4* src = (const float4*)(Wr1 + 96 * 256);
        float4* dst = (float4*)wr1c;
        #pragma unroll
        for (int r = 0; r < 4; ++r) dst[t + 512 * r] = src[t + 512 * r];
    }
    mc[t] = metric[b * 1024 + t];
    mc[t + 512] = metric[b * 1024 + t + 512];
    if (t < 256) Slds[t] = 0.f;
    __syncthreads();

    if (t < 256) {
        float acc = br1[t];
        #pragma unroll
        for (int m = 0; m < M; ++m) acc = fmaf(points[b * M + m], Wr1[m * 256 + t], acc);
        #pragma unroll
        for (int m = 0; m < M; ++m) acc = fmaf(mc[i * M + m], Wr1[(32 + m) * 256 + t], acc);
        bmi[t] = acc;
    }

    const int w = t >> 6, l = t & 63;
    const int ph = l >> 5, k = l & 31;
    const int j0 = 2 * w + ph, j1 = 16 + 2 * w + ph;
    const float gki  = mc[i * M + k] * TSCALE;   // metric symmetric
    const float gij0 = mc[i * M + j0] * TSCALE;
    const float gij1 = mc[i * M + j1] * TSCALE;
    const float gjk0 = mc[j0 * M + k] * TSCALE;
    const float gjk1 = mc[j1 * M + k] * TSCALE;
    __syncthreads();   // all mc(metric) reads done; bmi written

    // --- prefetch mj tiles: issue global loads now, consume after chris ---
    const float4* mj4 = (const float4*)(mj + b * M * 256);
    const int jb = w * 2;
    float4 p00 = mj4[(jb + 0) * 64 + l];
    float4 p01 = mj4[(jb + 1) * 64 + l];
    float4 p10 = mj4[(jb + 16) * 64 + l];
    float4 p11 = mj4[(jb + 17) * 64 + l];

    // --- christoffel: both j's in one pass, shared gki term ---
    float acc_a = 0.f, acc_b = 0.f;
    #pragma unroll 8
    for (int u = 0; u < H; ++u) {
        float tc = fmaf(gki, Wc1[2 * H + u], bc1s[u]);
        float pa = fmaf(gij0, Wc1[u], fmaf(gjk0, Wc1[H + u], tc));
        float pb = fmaf(gij1, Wc1[u], fmaf(gjk1, Wc1[H + u], tc));
        acc_a = fmaf(__builtin_amdgcn_rcpf(__builtin_amdgcn_exp2f(pa) + 1.f), Wc2[u], acc_a);
        acc_b = fmaf(__builtin_amdgcn_rcpf(__builtin_amdgcn_exp2f(pb) + 1.f), Wc2[u], acc_b);
    }
    const float KcV = Kc[0];
    // per-wave chris scratch overlays mc rows 4w..4w+3 (written & read by
    // wave w only — no barrier needed before ricci reads below)
    mc[w * 128 + l]      = fmaf(-2.f, acc_a, KcV);
    mc[w * 128 + 64 + l] = fmaf(-2.f, acc_b, KcV);

    // --- ricci layer-1: lane l owns dims 4l..4l+3 for the wave's 4 j's ---
    const float4* wr1c4 = (const float4*)wr1c;
    const float* chw = mc + w * 128;
    float4 bmiv = ((const float4*)bmi)[l];
    p00.x += bmiv.x; p00.y += bmiv.y; p00.z += bmiv.z; p00.w += bmiv.w;
    p01.x += bmiv.x; p01.y += bmiv.y; p01.z += bmiv.z; p01.w += bmiv.w;
    p10.x += bmiv.x; p10.y += bmiv.y; p10.z += bmiv.z; p10.w += bmiv.w;
    p11.x += bmiv.x; p11.y += bmiv.y; p11.z += bmiv.z; p11.w += bmiv.w;

    #define STEP(W, kk) { \
        float s0 = chw[(kk)];      float s1 = chw[32 + (kk)]; \
        float s2 = chw[64 + (kk)]; float s3 = chw[96 + (kk)]; \
        FMA4(p00, s0, W); FMA4(p01, s1, W); FMA4(p10, s2, W); FMA4(p11, s3, W); }

    #pragma unroll
    for (int kc = 0; kc < 4; ++kc) {
        const int kb = kc * 8;
        float4 w0 = wr1c4[(kb + 0) * 64 + l];
        float4 w1 = wr1c4[(kb + 1) * 64 + l];
        float4 w2 = wr1c4[(kb + 2) * 64 + l];
        float4 w3 = wr1c4[(kb + 3) * 64 + l];
        float4 w4 = wr1c4[(kb + 4) * 64 + l];
        float4 w5 = wr1c4[(kb + 5) * 64 + l];
        float4 w6 = wr1c4[(kb + 6) * 64 + l];
        float4 w7 = wr1c4[(kb + 7) * 64 + l];
        STEP(w0, kb + 0) STEP(w1, kb + 1) STEP(w2, kb + 2) STEP(w3, kb + 3)
        STEP(w4, kb + 4) STEP(w5, kb + 5) STEP(w6, kb + 6) STEP(w7, kb + 7)
    }
    #undef STEP

    float r0 = fmaxf(p00.x,0.f)+fmaxf(p01.x,0.f)+fmaxf(p10.x,0.f)+fmaxf(p11.x,0.f);
    float r1 = fmaxf(p00.y,0.f)+fmaxf(p01.y,0.f)+fmaxf(p10.y,0.f)+fmaxf(p11.y,0.f);
    float r2 = fmaxf(p00.z,0.f)+fmaxf(p01.z,0.f)+fmaxf(p10.z,0.f)+fmaxf(p11.z,0.f);
    float r3 = fmaxf(p00.w,0.f)+fmaxf(p01.w,0.f)+fmaxf(p10.w,0.f)+fmaxf(p11.w,0.f);
    atomicAdd(&Slds[4*l + 0], r0);
    atomicAdd(&Slds[4*l + 1], r1);
    atomicAdd(&Slds[4*l + 2], r2);
    atomicAdd(&Slds[4*l + 3], r3);
    __syncthreads();
    if (t < 256) atomicAdd(&S[b * 256 + t], Slds[t]);
    asm volatile("s_waitcnt vmcnt(0)" ::: "memory");  // S atomics done before cnt
    __syncthreads();
    if (t == 0) {
        int old = atomicAdd(&cnt[b], 1);
        finflag = (old == 31);
    }
    __syncthreads();
    if (!finflag) return;

    // ===== tiny epilogue (one block per b): ricci_dir via Wp, then MLPs =====
    float* fs   = wr1c;          // 256
    float* rdp  = wr1c + 256;    // 512
    float* pl   = wr1c + 768;    // 32
    float* fin  = wr1c + 800;    // 64
    float* hf   = wr1c + 864;    // 128
    float* npos = wr1c + 992;    // 32
    float* hh   = wr1c + 1024;   // 128

    if (t < 256) fs[t] = atomicAdd(&S[b * 256 + t], 0.f) * (1.f / 1024.f);
    if (t < M) pl[t] = points[b * M + t];
    __syncthreads();
    {
        const int ii = t & 31, ch = t >> 5;   // 16 chunks x 16 u's
        float part = 0.f;
        #pragma unroll
        for (int uu = 0; uu < 16; ++uu) {
            const int u = ch * 16 + uu;
            part = fmaf(fs[u], Wp[u * 1024 + b * 32 + ii], part);
        }
        rdp[t] = part;
    }
    __syncthreads();
    if (t < M) {
        float a = c2[b * 32 + t];
        #pragma unroll
        for (int ch = 0; ch < 16; ++ch) a += rdp[ch * 32 + t];
        fin[t] = pl[t];
        fin[M + t] = a;
    }
    __syncthreads();
    if (t < H) {
        float acc = bf1[t];
        #pragma unroll
        for (int m = 0; m < 2 * M; ++m) acc = fmaf(fin[m], Wf1[m * H + t], acc);
        hf[t] = fmaxf(acc, 0.f);
    }
    __syncthreads();
    if (t < M) {
        float acc = bf2[t];
        #pragma unroll
        for (int u = 0; u < H; ++u) acc = fmaf(hf[u], Wf2[u * M + t], acc);
        npos[t] = pl[t] + acc;
    }
    __syncthreads();
    if (t < H) {
        float acc = bh1[t];
        #pragma unroll
        for (int m = 0; m < M; ++m) acc = fmaf(npos[m], Wh1[m * H + t], acc);
        hh[t] = tanhf(acc);
    }
    __syncthreads();
    if (t < 2 * M) {
        float acc = bh2[t];
        #pragma unroll
        for (int u = 0; u < H; ++u) acc = fmaf(hh[u], Wh2[u * (2 * M) + t], acc);
        out[b * (2 * M) + t] = acc;
    }
}

extern "C" void kernel_launch(void* const* d_in, const int* in_sizes, int n_in,
                              void* d_out, int out_size, void* d_ws, size_t ws_size,
                              hipStream_t stream)
{
    const float* points = (const float*)d_in[0];
    const float* Wm1 = (const float*)d_in[1];
    const float* bm1 = (const float*)d_in[2];
    const float* Wm2 = (const float*)d_in[3];
    const float* bm2 = (const float*)d_in[4];
    const float* Wc1 = (const float*)d_in[5];
    const float* bc1 = (const float*)d_in[6];
    const float* Wc2 = (const float*)d_in[7];
    const float* bc2 = (const float*)d_in[8];
    const float* Wr1 = (const float*)d_in[9];
    const float* br1 = (const float*)d_in[10];
    const float* Wr2 = (const float*)d_in[11];
    const float* br2 = (const float*)d_in[12];
    const float* Wf1 = (const float*)d_in[13];
    const float* bf1 = (const float*)d_in[14];
    const float* Wf2 = (const float*)d_in[15];
    const float* bf2 = (const float*)d_in[16];
    const float* Wh1 = (const float*)d_in[17];
    const float* bh1 = (const float*)d_in[18];
    const float* Wh2 = (const float*)d_in[19];
    const float* bh2 = (const float*)d_in[20];
    float* out = (float*)d_out;

    float* ws     = (float*)d_ws;
    float* metric = ws;                    // 32768
    float* mj     = ws + 32768;            // 262144
    float* S      = ws + 294912;           // 8192
    float* bc1s   = ws + 303104;           // 128
    float* Kc     = ws + 303232;           // 1
    int*   cnt    = (int*)(ws + 303236);   // 32 ints
    float* Wp     = ws + 303268;           // 262144
    float* c2     = ws + 565412;           // 1024

    k_prep<<<289, 256, 0, stream>>>(points, Wm1, bm1, Wm2, bm2, Wr1, bc1, Wc2,
                                    bc2, Wr2, br2, metric, mj, S, bc1s, Kc,
                                    cnt, Wp, c2);
    k_main<<<B * M, 512, 0, stream>>>(points, metric, mj, Wc1, Wc2, bc1s, Kc,
                                      Wr1, br1, S, cnt,
                                      Wp, c2, Wf1, bf1, Wf2, bf2,
                                      Wh1, bh1, Wh2, bh2, out);
}

// Round 12
// 68.795 us; speedup vs baseline: 1.1510x; 1.1510x over previous
//
#include <hip/hip_runtime.h>

#define B 32
#define M 32
#define H 128
#define EPS 1e-6f
#define TSCALE 2.8853900817779268f   // 2*log2(e)

// ---------------- workspace layout (floats) ----------------
// metric @ 0      : 32768
// mj     @ 32768  : 262144   mj[b][j][d] = metric[b,j,:] @ Wr1[64:96]
// S      @ 294912 : 8192
// bc1s   @ 303104 : 128      bc1 * 2log2(e)
// Kc     @ 303232 : 1        sum(Wc2) + bc2
// cnt    @ 303236 : 32 ints
// Wp     @ 303268 : 262144   Wp[u][b][i] = sum_j sym(Wr2)[u,i,j] * p[b,j]
// c2     @ 565412 : 1024     c2[b][i]    = sum_j sym(br2)[i,j] * p[b,j]

#define FMA4(P, s, W) \
    P.x = fmaf((s), (W).x, P.x); P.y = fmaf((s), (W).y, P.y); \
    P.z = fmaf((s), (W).z, P.z); P.w = fmaf((s), (W).w, P.w);

// Kernel 1, grid 289: blocks 0-31 = per-b prep (metric, mj, zero S/cnt,
// chris constants); blocks 32-287 = Wp row u = blk-32; block 288 = c2.
// LDS buffers padded (33/36-float rows) to kill 8/32-way bank conflicts.
__global__ __launch_bounds__(256) void k_prep(
    const float* __restrict__ points, const float* __restrict__ Wm1,
    const float* __restrict__ bm1, const float* __restrict__ Wm2,
    const float* __restrict__ bm2, const float* __restrict__ Wr1,
    const float* __restrict__ bc1, const float* __restrict__ Wc2,
    const float* __restrict__ bc2, const float* __restrict__ Wr2,
    const float* __restrict__ br2,
    float* __restrict__ metric, float* __restrict__ mj,
    float* __restrict__ S, float* __restrict__ bc1s, float* __restrict__ Kc,
    int* __restrict__ cnt, float* __restrict__ Wp, float* __restrict__ c2)
{
    __shared__ float sbuf[3392];
    const int role = blockIdx.x, t = threadIdx.x;

    if (role >= B) {
        // ---- Wp / c2 path: symmetrize one Wr2 row, contract with points ----
        const int u = role - B;                 // 0..255 = Wr2 row, 256 = br2
        float* row    = sbuf;                   // [32][33] = 1056
        float* rowsym = sbuf + 1056;            // [32][36] = 1152
        float* ps     = sbuf + 2208;            // [32][36] = 1152
        const float* src = (u < 256) ? (Wr2 + u * 1024) : br2;
        #pragma unroll
        for (int r = 0; r < 4; ++r) {
            const int d = t + 256 * r;
            row[(d >> 5) * 33 + (d & 31)] = src[d];
            ps[(d >> 5) * 36 + (d & 31)]  = points[d];
        }
        __syncthreads();
        #pragma unroll
        for (int r = 0; r < 4; ++r) {
            const int d = t + 256 * r, ii = d >> 5, jj = d & 31;
            rowsym[ii * 36 + jj] = 0.5f * (row[ii * 33 + jj] + row[jj * 33 + ii]);
        }
        __syncthreads();
        const int b = t >> 3, i0 = (t & 7) * 4;
        const float4* rs4 = (const float4*)rowsym;      // row stride 9 float4
        const float4* p4  = (const float4*)(ps + b * 36);
        float4 o; o.x = o.y = o.z = o.w = 0.f;
        #pragma unroll
        for (int m = 0; m < 8; ++m) {
            const float4 pv = p4[m];
            const float4 r0 = rs4[(i0 + 0) * 9 + m];
            const float4 r1 = rs4[(i0 + 1) * 9 + m];
            const float4 r2 = rs4[(i0 + 2) * 9 + m];
            const float4 r3 = rs4[(i0 + 3) * 9 + m];
            o.x = fmaf(pv.x, r0.x, fmaf(pv.y, r0.y, fmaf(pv.z, r0.z, fmaf(pv.w, r0.w, o.x))));
            o.y = fmaf(pv.x, r1.x, fmaf(pv.y, r1.y, fmaf(pv.z, r1.z, fmaf(pv.w, r1.w, o.y))));
            o.z = fmaf(pv.x, r2.x, fmaf(pv.y, r2.y, fmaf(pv.z, r2.z, fmaf(pv.w, r2.w, o.z))));
            o.w = fmaf(pv.x, r3.x, fmaf(pv.y, r3.y, fmaf(pv.z, r3.z, fmaf(pv.w, r3.w, o.w))));
        }
        if (u < 256) ((float4*)(Wp + u * 1024 + b * 32))[t & 7] = o;
        else         ((float4*)(c2 + b * 32))[t & 7] = o;
        return;
    }

    // ---- per-b prep path ----
    const int b = role;
    float* p     = sbuf;           // 32
    float* h     = sbuf + 32;      // 128
    float* comps = sbuf + 160;     // [32][33] = 1056
    float* msym  = sbuf + 1216;    // 1024
    if (t < M) p[t] = points[b * M + t];
    __syncthreads();
    if (t < H) {
        float acc = bm1[t];
        #pragma unroll
        for (int m = 0; m < M; ++m) acc = fmaf(p[m], Wm1[m * H + t], acc);
        h[t] = fmaxf(acc, 0.f);
    }
    __syncthreads();
    #pragma unroll
    for (int r = 0; r < 4; ++r) {
        const int d = t + 256 * r;
        float acc = bm2[d];
        for (int u = 0; u < H; ++u) acc = fmaf(h[u], Wm2[u * (M * M) + d], acc);
        comps[(d >> 5) * 33 + (d & 31)] = acc;
    }
    __syncthreads();
    #pragma unroll
    for (int r = 0; r < 4; ++r) {
        const int d = t + 256 * r;
        const int ii = d >> 5, jj = d & 31;
        float v = 0.5f * (comps[ii * 33 + jj] + comps[jj * 33 + ii]) + (ii == jj ? EPS : 0.f);
        metric[b * M * M + d] = v;
        msym[d] = v;
    }
    S[b * 256 + t] = 0.f;
    if (t == 0) cnt[b] = 0;
    __syncthreads();
    float wreg[M];
    #pragma unroll
    for (int m = 0; m < M; ++m) wreg[m] = Wr1[(64 + m) * 256 + t];
    const float4* msym4 = (const float4*)msym;   // broadcast reads (same addr)
    for (int x = 0; x < M; ++x) {
        float acc = 0.f;
        #pragma unroll
        for (int mq = 0; mq < 8; ++mq) {
            float4 mv = msym4[x * 8 + mq];
            acc = fmaf(mv.x, wreg[4 * mq + 0], acc);
            acc = fmaf(mv.y, wreg[4 * mq + 1], acc);
            acc = fmaf(mv.z, wreg[4 * mq + 2], acc);
            acc = fmaf(mv.w, wreg[4 * mq + 3], acc);
        }
        mj[(b * M + x) * 256 + t] = acc;
    }
    if (b == 0) {
        if (t < H) bc1s[t] = bc1[t] * TSCALE;
        if (t == 0) {
            float s = bc2[0];
            for (int u = 0; u < H; ++u) s += Wc2[u];
            Kc[0] = s;
        }
    }
}

// Kernel 2: per block (b,i): christoffel MLP + ricci layer-1 + reduce into
// S[b]; the 32nd finishing block per b runs the tiny Wp-based epilogue.
// 512 threads = 8 waves. LDS ~39 KB -> 4 blocks/CU.
// b = blk&31, i = blk>>5: all 32 blocks of a given b land on XCD b%8 ->
// mj/metric reads and S atomics are XCD-L2-local.
// Chris values packed [k][4 j-slots] so the ricci STEP reads one broadcast
// ds_read_b128 instead of 4 ds_read_b32 (LDS pipe was the loaded pipe).
__global__ __launch_bounds__(512, 6) void k_main(
    const float* __restrict__ points, const float* __restrict__ metric,
    const float* __restrict__ mj, const float* __restrict__ Wc1,
    const float* __restrict__ Wc2, const float* __restrict__ bc1s,
    const float* __restrict__ Kc, const float* __restrict__ Wr1,
    const float* __restrict__ br1, float* __restrict__ S,
    int* __restrict__ cnt,
    const float* __restrict__ Wp, const float* __restrict__ c2,
    const float* __restrict__ Wf1, const float* __restrict__ bf1,
    const float* __restrict__ Wf2, const float* __restrict__ bf2,
    const float* __restrict__ Wh1, const float* __restrict__ bh1,
    const float* __restrict__ Wh2, const float* __restrict__ bh2,
    float* __restrict__ out)
{
    const int blk = blockIdx.x;
    const int b = blk & 31, i = blk >> 5;
    const int t = threadIdx.x;

    __shared__ float wr1c[M * 256];   // Wr1[96:128] — 32 KB (epilogue scratch later)
    __shared__ float mc[M * M];       // metric[b] first, per-wave chris scratch after
    __shared__ float bmi[256];
    __shared__ float Slds[256];
    __shared__ int finflag;

    {
        const float4* src = (const float4*)(Wr1 + 96 * 256);
        float4* dst = (float4*)wr1c;
        #pragma unroll
        for (int r = 0; r < 4; ++r) dst[t + 512 * r] = src[t + 512 * r];
    }
    mc[t] = metric[b * 1024 + t];
    mc[t + 512] = metric[b * 1024 + t + 512];
    if (t < 256) Slds[t] = 0.f;
    __syncthreads();

    if (t < 256) {
        float acc = br1[t];
        #pragma unroll
        for (int m = 0; m < M; ++m) acc = fmaf(points[b * M + m], Wr1[m * 256 + t], acc);
        #pragma unroll
        for (int m = 0; m < M; ++m) acc = fmaf(mc[i * M + m], Wr1[(32 + m) * 256 + t], acc);
        bmi[t] = acc;
    }

    const int w = t >> 6, l = t & 63;
    const int ph = l >> 5, k = l & 31;
    const int j0 = 2 * w + ph, j1 = 16 + 2 * w + ph;
    const float gki  = mc[i * M + k] * TSCALE;   // metric symmetric
    const float gij0 = mc[i * M + j0] * TSCALE;
    const float gij1 = mc[i * M + j1] * TSCALE;
    const float gjk0 = mc[j0 * M + k] * TSCALE;
    const float gjk1 = mc[j1 * M + k] * TSCALE;
    __syncthreads();   // all mc(metric) reads done; bmi written

    // --- prefetch mj tiles: issue global loads now, consume after chris ---
    const float4* mj4 = (const float4*)(mj + b * M * 256);
    const int jb = w * 2;
    float4 p00 = mj4[(jb + 0) * 64 + l];
    float4 p01 = mj4[(jb + 1) * 64 + l];
    float4 p10 = mj4[(jb + 16) * 64 + l];
    float4 p11 = mj4[(jb + 17) * 64 + l];

    // --- christoffel: both j's in one pass, shared gki term ---
    float acc_a = 0.f, acc_b = 0.f;
    #pragma unroll 8
    for (int u = 0; u < H; ++u) {
        float tc = fmaf(gki, Wc1[2 * H + u], bc1s[u]);
        float pa = fmaf(gij0, Wc1[u], fmaf(gjk0, Wc1[H + u], tc));
        float pb = fmaf(gij1, Wc1[u], fmaf(gjk1, Wc1[H + u], tc));
        acc_a = fmaf(__builtin_amdgcn_rcpf(__builtin_amdgcn_exp2f(pa) + 1.f), Wc2[u], acc_a);
        acc_b = fmaf(__builtin_amdgcn_rcpf(__builtin_amdgcn_exp2f(pb) + 1.f), Wc2[u], acc_b);
    }
    const float KcV = Kc[0];
    // per-wave chris scratch overlays mc rows 4w..4w+3, packed [k][slot]:
    // slot {0:j=2w, 1:j=2w+1, 2:j=16+2w, 3:j=17+2w} -> one b128 read per k.
    // ca: j=2w+ph -> slot ph; cb: j=16+2w+ph -> slot 2+ph. Wave-private.
    mc[w * 128 + k * 4 + ph]     = fmaf(-2.f, acc_a, KcV);
    mc[w * 128 + k * 4 + 2 + ph] = fmaf(-2.f, acc_b, KcV);

    // --- ricci layer-1: lane l owns dims 4l..4l+3 for the wave's 4 j's ---
    const float4* wr1c4 = (const float4*)wr1c;
    const float4* ch4 = (const float4*)(mc + w * 128);   // broadcast reads
    float4 bmiv = ((const float4*)bmi)[l];
    p00.x += bmiv.x; p00.y += bmiv.y; p00.z += bmiv.z; p00.w += bmiv.w;
    p01.x += bmiv.x; p01.y += bmiv.y; p01.z += bmiv.z; p01.w += bmiv.w;
    p10.x += bmiv.x; p10.y += bmiv.y; p10.z += bmiv.z; p10.w += bmiv.w;
    p11.x += bmiv.x; p11.y += bmiv.y; p11.z += bmiv.z; p11.w += bmiv.w;

    #define STEP(W, kk) { \
        float4 s = ch4[kk]; \
        FMA4(p00, s.x, W); FMA4(p01, s.y, W); FMA4(p10, s.z, W); FMA4(p11, s.w, W); }

    #pragma unroll
    for (int kc = 0; kc < 4; ++kc) {
        const int kb = kc * 8;
        float4 w0 = wr1c4[(kb + 0) * 64 + l];
        float4 w1 = wr1c4[(kb + 1) * 64 + l];
        float4 w2 = wr1c4[(kb + 2) * 64 + l];
        float4 w3 = wr1c4[(kb + 3) * 64 + l];
        float4 w4 = wr1c4[(kb + 4) * 64 + l];
        float4 w5 = wr1c4[(kb + 5) * 64 + l];
        float4 w6 = wr1c4[(kb + 6) * 64 + l];
        float4 w7 = wr1c4[(kb + 7) * 64 + l];
        STEP(w0, kb + 0) STEP(w1, kb + 1) STEP(w2, kb + 2) STEP(w3, kb + 3)
        STEP(w4, kb + 4) STEP(w5, kb + 5) STEP(w6, kb + 6) STEP(w7, kb + 7)
    }
    #undef STEP

    float r0 = fmaxf(p00.x,0.f)+fmaxf(p01.x,0.f)+fmaxf(p10.x,0.f)+fmaxf(p11.x,0.f);
    float r1 = fmaxf(p00.y,0.f)+fmaxf(p01.y,0.f)+fmaxf(p10.y,0.f)+fmaxf(p11.y,0.f);
    float r2 = fmaxf(p00.z,0.f)+fmaxf(p01.z,0.f)+fmaxf(p10.z,0.f)+fmaxf(p11.z,0.f);
    float r3 = fmaxf(p00.w,0.f)+fmaxf(p01.w,0.f)+fmaxf(p10.w,0.f)+fmaxf(p11.w,0.f);
    atomicAdd(&Slds[4*l + 0], r0);
    atomicAdd(&Slds[4*l + 1], r1);
    atomicAdd(&Slds[4*l + 2], r2);
    atomicAdd(&Slds[4*l + 3], r3);
    __syncthreads();
    if (t < 256) atomicAdd(&S[b * 256 + t], Slds[t]);
    asm volatile("s_waitcnt vmcnt(0)" ::: "memory");  // S atomics done before cnt
    __syncthreads();
    if (t == 0) {
        int old = atomicAdd(&cnt[b], 1);
        finflag = (old == 31);
    }
    __syncthreads();
    if (!finflag) return;

    // ===== tiny epilogue (one block per b): ricci_dir via Wp, then MLPs =====
    float* fs   = wr1c;          // 256
    float* rdp  = wr1c + 256;    // 512
    float* pl   = wr1c + 768;    // 32
    float* fin  = wr1c + 800;    // 64
    float* hf   = wr1c + 864;    // 128
    float* npos = wr1c + 992;    // 32
    float* hh   = wr1c + 1024;   // 128

    if (t < 256) fs[t] = atomicAdd(&S[b * 256 + t], 0.f) * (1.f / 1024.f);
    if (t < M) pl[t] = points[b * M + t];
    __syncthreads();
    {
        const int ii = t & 31, ch = t >> 5;   // 16 chunks x 16 u's
        float part = 0.f;
        #pragma unroll
        for (int uu = 0; uu < 16; ++uu) {
            const int u = ch * 16 + uu;
            part = fmaf(fs[u], Wp[u * 1024 + b * 32 + ii], part);
        }
        rdp[t] = part;
    }
    __syncthreads();
    if (t < M) {
        float a = c2[b * 32 + t];
        #pragma unroll
        for (int ch = 0; ch < 16; ++ch) a += rdp[ch * 32 + t];
        fin[t] = pl[t];
        fin[M + t] = a;
    }
    __syncthreads();
    if (t < H) {
        float acc = bf1[t];
        #pragma unroll
        for (int m = 0; m < 2 * M; ++m) acc = fmaf(fin[m], Wf1[m * H + t], acc);
        hf[t] = fmaxf(acc, 0.f);
    }
    __syncthreads();
    if (t < M) {
        float acc = bf2[t];
        #pragma unroll
        for (int u = 0; u < H; ++u) acc = fmaf(hf[u], Wf2[u * M + t], acc);
        npos[t] = pl[t] + acc;
    }
    __syncthreads();
    if (t < H) {
        float acc = bh1[t];
        #pragma unroll
        for (int m = 0; m < M; ++m) acc = fmaf(npos[m], Wh1[m * H + t], acc);
        hh[t] = tanhf(acc);
    }
    __syncthreads();
    if (t < 2 * M) {
        float acc = bh2[t];
        #pragma unroll
        for (int u = 0; u < H; ++u) acc = fmaf(hh[u], Wh2[u * (2 * M) + t], acc);
        out[b * (2 * M) + t] = acc;
    }
}

extern "C" void kernel_launch(void* const* d_in, const int* in_sizes, int n_in,
                              void* d_out, int out_size, void* d_ws, size_t ws_size,
                              hipStream_t stream)
{
    const float* points = (const float*)d_in[0];
    const float* Wm1 = (const float*)d_in[1];
    const float* bm1 = (const float*)d_in[2];
    const float* Wm2 = (const float*)d_in[3];
    const float* bm2 = (const float*)d_in[4];
    const float* Wc1 = (const float*)d_in[5];
    const float* bc1 = (const float*)d_in[6];
    const float* Wc2 = (const float*)d_in[7];
    const float* bc2 = (const float*)d_in[8];
    const float* Wr1 = (const float*)d_in[9];
    const float* br1 = (const float*)d_in[10];
    const float* Wr2 = (const float*)d_in[11];
    const float* br2 = (const float*)d_in[12];
    const float* Wf1 = (const float*)d_in[13];
    const float* bf1 = (const float*)d_in[14];
    const float* Wf2 = (const float*)d_in[15];
    const float* bf2 = (const float*)d_in[16];
    const float* Wh1 = (const float*)d_in[17];
    const float* bh1 = (const float*)d_in[18];
    const float* Wh2 = (const float*)d_in[19];
    const float* bh2 = (const float*)d_in[20];
    float* out = (float*)d_out;

    float* ws     = (float*)d_ws;
    float* metric = ws;                    // 32768
    float* mj     = ws + 32768;            // 262144
    float* S      = ws + 294912;           // 8192
    float* bc1s   = ws + 303104;           // 128
    float* Kc     = ws + 303232;           // 1
    int*   cnt    = (int*)(ws + 303236);   // 32 ints
    float* Wp     = ws + 303268;           // 262144
    float* c2     = ws + 565412;           // 1024

    k_prep<<<289, 256, 0, stream>>>(points, Wm1, bm1, Wm2, bm2, Wr1, bc1, Wc2,
                                    bc2, Wr2, br2, metric, mj, S, bc1s, Kc,
                                    cnt, Wp, c2);
    k_main<<<B * M, 512, 0, stream>>>(points, metric, mj, Wc1, Wc2, bc1s, Kc,
                                      Wr1, br1, S, cnt,
                                      Wp, c2, Wf1, bf1, Wf2, bf2,
                                      Wh1, bh1, Wh2, bh2, out);
}

// Round 13
// 60.424 us; speedup vs baseline: 1.3104x; 1.1385x over previous
//
#include <hip/hip_runtime.h>

#define B 32
#define M 32
#define H 128
#define EPS 1e-6f
#define TSCALE 2.8853900817779268f   // 2*log2(e)

typedef float v2f __attribute__((ext_vector_type(2)));
typedef float v4f __attribute__((ext_vector_type(4)));

static __device__ __forceinline__ v2f splat2(float x) { return (v2f){x, x}; }
static __device__ __forceinline__ v4f splat4(float x) { return (v4f){x, x, x, x}; }
static __device__ __forceinline__ v2f fma2(v2f a, v2f b, v2f c) {
    return __builtin_elementwise_fma(a, b, c);
}
static __device__ __forceinline__ v4f fma4(v4f a, v4f b, v4f c) {
    return __builtin_elementwise_fma(a, b, c);
}

// ---------------- workspace layout (floats) ----------------
// metric @ 0      : 32768
// mj     @ 32768  : 262144   mj[b][j][d] = metric[b,j,:] @ Wr1[64:96]
// S      @ 294912 : 8192
// bc1s   @ 303104 : 128      bc1 * 2log2(e)
// Kc     @ 303232 : 1        sum(Wc2) + bc2
// cnt    @ 303236 : 32 ints
// Wp     @ 303268 : 262144   Wp[u][b][i] = sum_j sym(Wr2)[u,i,j] * p[b,j]
// c2     @ 565412 : 1024     c2[b][i]    = sum_j sym(br2)[i,j] * p[b,j]

#define FMA4(P, s, W) \
    P.x = fmaf((s), (W).x, P.x); P.y = fmaf((s), (W).y, P.y); \
    P.z = fmaf((s), (W).z, P.z); P.w = fmaf((s), (W).w, P.w);

// Kernel 1, grid 289: blocks 0-31 = per-b prep (metric, mj, zero S/cnt,
// chris constants); blocks 32-287 = Wp row u = blk-32; block 288 = c2.
// LDS buffers padded (33/36-float rows) to kill 8/32-way bank conflicts.
__global__ __launch_bounds__(256) void k_prep(
    const float* __restrict__ points, const float* __restrict__ Wm1,
    const float* __restrict__ bm1, const float* __restrict__ Wm2,
    const float* __restrict__ bm2, const float* __restrict__ Wr1,
    const float* __restrict__ bc1, const float* __restrict__ Wc2,
    const float* __restrict__ bc2, const float* __restrict__ Wr2,
    const float* __restrict__ br2,
    float* __restrict__ metric, float* __restrict__ mj,
    float* __restrict__ S, float* __restrict__ bc1s, float* __restrict__ Kc,
    int* __restrict__ cnt, float* __restrict__ Wp, float* __restrict__ c2)
{
    __shared__ float sbuf[3392];
    const int role = blockIdx.x, t = threadIdx.x;

    if (role >= B) {
        // ---- Wp / c2 path: symmetrize one Wr2 row, contract with points ----
        const int u = role - B;                 // 0..255 = Wr2 row, 256 = br2
        float* row    = sbuf;                   // [32][33] = 1056
        float* rowsym = sbuf + 1056;            // [32][36] = 1152
        float* ps     = sbuf + 2208;            // [32][36] = 1152
        const float* src = (u < 256) ? (Wr2 + u * 1024) : br2;
        #pragma unroll
        for (int r = 0; r < 4; ++r) {
            const int d = t + 256 * r;
            row[(d >> 5) * 33 + (d & 31)] = src[d];
            ps[(d >> 5) * 36 + (d & 31)]  = points[d];
        }
        __syncthreads();
        #pragma unroll
        for (int r = 0; r < 4; ++r) {
            const int d = t + 256 * r, ii = d >> 5, jj = d & 31;
            rowsym[ii * 36 + jj] = 0.5f * (row[ii * 33 + jj] + row[jj * 33 + ii]);
        }
        __syncthreads();
        const int b = t >> 3, i0 = (t & 7) * 4;
        const float4* rs4 = (const float4*)rowsym;      // row stride 9 float4
        const float4* p4  = (const float4*)(ps + b * 36);
        float4 o; o.x = o.y = o.z = o.w = 0.f;
        #pragma unroll
        for (int m = 0; m < 8; ++m) {
            const float4 pv = p4[m];
            const float4 r0 = rs4[(i0 + 0) * 9 + m];
            const float4 r1 = rs4[(i0 + 1) * 9 + m];
            const float4 r2 = rs4[(i0 + 2) * 9 + m];
            const float4 r3 = rs4[(i0 + 3) * 9 + m];
            o.x = fmaf(pv.x, r0.x, fmaf(pv.y, r0.y, fmaf(pv.z, r0.z, fmaf(pv.w, r0.w, o.x))));
            o.y = fmaf(pv.x, r1.x, fmaf(pv.y, r1.y, fmaf(pv.z, r1.z, fmaf(pv.w, r1.w, o.y))));
            o.z = fmaf(pv.x, r2.x, fmaf(pv.y, r2.y, fmaf(pv.z, r2.z, fmaf(pv.w, r2.w, o.z))));
            o.w = fmaf(pv.x, r3.x, fmaf(pv.y, r3.y, fmaf(pv.z, r3.z, fmaf(pv.w, r3.w, o.w))));
        }
        if (u < 256) ((float4*)(Wp + u * 1024 + b * 32))[t & 7] = o;
        else         ((float4*)(c2 + b * 32))[t & 7] = o;
        return;
    }

    // ---- per-b prep path ----
    const int b = role;
    float* p     = sbuf;           // 32
    float* h     = sbuf + 32;      // 128
    float* comps = sbuf + 160;     // [32][33] = 1056
    float* msym  = sbuf + 1216;    // 1024
    if (t < M) p[t] = points[b * M + t];
    __syncthreads();
    if (t < H) {
        float acc = bm1[t];
        #pragma unroll
        for (int m = 0; m < M; ++m) acc = fmaf(p[m], Wm1[m * H + t], acc);
        h[t] = fmaxf(acc, 0.f);
    }
    __syncthreads();
    // comps: thread t owns d-block 4t..4t+3 (one row, 4 consecutive cols);
    // b128 Wm2 loads, float4 h broadcasts — 4x fewer VMEM/LDS issues.
    {
        float4 acc = ((const float4*)bm2)[t];
        const float4* Wm2_4 = (const float4*)Wm2;     // row stride 256 float4
        const float4* h4 = (const float4*)h;
        #pragma unroll 2
        for (int u4 = 0; u4 < 32; ++u4) {
            const float4 hv = h4[u4];
            const float4 w0 = Wm2_4[(u4 * 4 + 0) * 256 + t];
            const float4 w1 = Wm2_4[(u4 * 4 + 1) * 256 + t];
            const float4 w2 = Wm2_4[(u4 * 4 + 2) * 256 + t];
            const float4 w3 = Wm2_4[(u4 * 4 + 3) * 256 + t];
            FMA4(acc, hv.x, w0); FMA4(acc, hv.y, w1);
            FMA4(acc, hv.z, w2); FMA4(acc, hv.w, w3);
        }
        const int row = t >> 3, col0 = (t & 7) * 4;
        comps[row * 33 + col0 + 0] = acc.x;
        comps[row * 33 + col0 + 1] = acc.y;
        comps[row * 33 + col0 + 2] = acc.z;
        comps[row * 33 + col0 + 3] = acc.w;
    }
    __syncthreads();
    {
        const int row = t >> 3, col0 = (t & 7) * 4;
        #pragma unroll
        for (int c = 0; c < 4; ++c) {
            const int d = 4 * t + c, ii = row, jj = col0 + c;
            float v = 0.5f * (comps[ii * 33 + jj] + comps[jj * 33 + ii]) + (ii == jj ? EPS : 0.f);
            metric[b * M * M + d] = v;
            msym[d] = v;
        }
    }
    S[b * 256 + t] = 0.f;
    if (t == 0) cnt[b] = 0;
    __syncthreads();
    float wreg[M];
    #pragma unroll
    for (int m = 0; m < M; ++m) wreg[m] = Wr1[(64 + m) * 256 + t];
    const float4* msym4 = (const float4*)msym;   // broadcast reads (same addr)
    #pragma unroll 2
    for (int x = 0; x < M; ++x) {
        float acc = 0.f;
        #pragma unroll
        for (int mq = 0; mq < 8; ++mq) {
            float4 mv = msym4[x * 8 + mq];
            acc = fmaf(mv.x, wreg[4 * mq + 0], acc);
            acc = fmaf(mv.y, wreg[4 * mq + 1], acc);
            acc = fmaf(mv.z, wreg[4 * mq + 2], acc);
            acc = fmaf(mv.w, wreg[4 * mq + 3], acc);
        }
        mj[(b * M + x) * 256 + t] = acc;
    }
    if (b == 0) {
        if (t < H) bc1s[t] = bc1[t] * TSCALE;
        if (t == 0) {
            float s = bc2[0];
            for (int u = 0; u < H; ++u) s += Wc2[u];
            Kc[0] = s;
        }
    }
}

// Kernel 2: per block (b,i): christoffel MLP + ricci layer-1 + reduce into
// S[b]; the 32nd finishing block per b runs the tiny Wp-based epilogue.
// 512 threads = 8 waves. LDS ~39 KB -> 4 blocks/CU.
// b = blk&31, i = blk>>5: all 32 same-b blocks land on XCD b%8 (L2-local).
// chris/ricci math written on v2f/v4f so the backend can emit v_pk_fma_f32.
__global__ __launch_bounds__(512, 6) void k_main(
    const float* __restrict__ points, const float* __restrict__ metric,
    const float* __restrict__ mj, const float* __restrict__ Wc1,
    const float* __restrict__ Wc2, const float* __restrict__ bc1s,
    const float* __restrict__ Kc, const float* __restrict__ Wr1,
    const float* __restrict__ br1, float* __restrict__ S,
    int* __restrict__ cnt,
    const float* __restrict__ Wp, const float* __restrict__ c2,
    const float* __restrict__ Wf1, const float* __restrict__ bf1,
    const float* __restrict__ Wf2, const float* __restrict__ bf2,
    const float* __restrict__ Wh1, const float* __restrict__ bh1,
    const float* __restrict__ Wh2, const float* __restrict__ bh2,
    float* __restrict__ out)
{
    const int blk = blockIdx.x;
    const int b = blk & 31, i = blk >> 5;
    const int t = threadIdx.x;

    __shared__ float wr1c[M * 256];   // Wr1[96:128] — 32 KB (epilogue scratch later)
    __shared__ float mc[M * M];       // metric[b] first, per-wave chris scratch after
    __shared__ float bmi[256];
    __shared__ float Slds[256];
    __shared__ int finflag;

    {
        const float4* src = (const float4*)(Wr1 + 96 * 256);
        float4* dst = (float4*)wr1c;
        #pragma unroll
        for (int r = 0; r < 4; ++r) dst[t + 512 * r] = src[t + 512 * r];
    }
    mc[t] = metric[b * 1024 + t];
    mc[t + 512] = metric[b * 1024 + t + 512];
    if (t < 256) Slds[t] = 0.f;
    __syncthreads();

    if (t < 256) {
        float acc = br1[t];
        #pragma unroll
        for (int m = 0; m < M; ++m) acc = fmaf(points[b * M + m], Wr1[m * 256 + t], acc);
        #pragma unroll
        for (int m = 0; m < M; ++m) acc = fmaf(mc[i * M + m], Wr1[(32 + m) * 256 + t], acc);
        bmi[t] = acc;
    }

    const int w = t >> 6, l = t & 63;
    const int ph = l >> 5, k = l & 31;
    const int j0 = 2 * w + ph, j1 = 16 + 2 * w + ph;
    const float gki  = mc[i * M + k] * TSCALE;   // metric symmetric
    const v2f gijv = {mc[i * M + j0] * TSCALE, mc[i * M + j1] * TSCALE};
    const v2f gjkv = {mc[j0 * M + k] * TSCALE, mc[j1 * M + k] * TSCALE};
    __syncthreads();   // all mc(metric) reads done; bmi written

    // --- prefetch mj tiles: issue global loads now, consume after chris ---
    const v4f* mj4 = (const v4f*)(mj + b * M * 256);
    const int jb = w * 2;
    v4f p00 = mj4[(jb + 0) * 64 + l];
    v4f p01 = mj4[(jb + 1) * 64 + l];
    v4f p10 = mj4[(jb + 16) * 64 + l];
    v4f p11 = mj4[(jb + 17) * 64 + l];

    // --- christoffel: (j0,j1) pair as v2f -> v_pk_fma_f32 ---
    v2f acc2 = {0.f, 0.f};
    #pragma unroll 8
    for (int u = 0; u < H; ++u) {
        const float tc = fmaf(gki, Wc1[2 * H + u], bc1s[u]);
        v2f pre = fma2(gijv, splat2(Wc1[u]), fma2(gjkv, splat2(Wc1[H + u]), splat2(tc)));
        v2f e = {__builtin_amdgcn_exp2f(pre.x), __builtin_amdgcn_exp2f(pre.y)};
        e += (v2f){1.f, 1.f};
        const v2f r = {__builtin_amdgcn_rcpf(e.x), __builtin_amdgcn_rcpf(e.y)};
        acc2 = fma2(r, splat2(Wc2[u]), acc2);
    }
    const float KcV = Kc[0];
    // per-wave chris scratch overlays mc rows 4w..4w+3, packed [k][slot]:
    // slot {0:j=2w, 1:j=2w+1, 2:j=16+2w, 3:j=17+2w} -> one b128 read per k.
    mc[w * 128 + k * 4 + ph]     = fmaf(-2.f, acc2.x, KcV);
    mc[w * 128 + k * 4 + 2 + ph] = fmaf(-2.f, acc2.y, KcV);

    // --- ricci layer-1: lane l owns dims 4l..4l+3 for the wave's 4 j's ---
    const v4f* wr1c4 = (const v4f*)wr1c;
    const v4f* ch4 = (const v4f*)(mc + w * 128);   // broadcast reads
    const v4f bmiv = ((const v4f*)bmi)[l];
    p00 += bmiv; p01 += bmiv; p10 += bmiv; p11 += bmiv;

    #define STEP(W, kk) { \
        const v4f s = ch4[kk]; \
        p00 = fma4(splat4(s.x), W, p00); p01 = fma4(splat4(s.y), W, p01); \
        p10 = fma4(splat4(s.z), W, p10); p11 = fma4(splat4(s.w), W, p11); }

    #pragma unroll
    for (int kc = 0; kc < 4; ++kc) {
        const int kb = kc * 8;
        const v4f w0 = wr1c4[(kb + 0) * 64 + l];
        const v4f w1 = wr1c4[(kb + 1) * 64 + l];
        const v4f w2 = wr1c4[(kb + 2) * 64 + l];
        const v4f w3 = wr1c4[(kb + 3) * 64 + l];
        const v4f w4 = wr1c4[(kb + 4) * 64 + l];
        const v4f w5 = wr1c4[(kb + 5) * 64 + l];
        const v4f w6 = wr1c4[(kb + 6) * 64 + l];
        const v4f w7 = wr1c4[(kb + 7) * 64 + l];
        STEP(w0, kb + 0) STEP(w1, kb + 1) STEP(w2, kb + 2) STEP(w3, kb + 3)
        STEP(w4, kb + 4) STEP(w5, kb + 5) STEP(w6, kb + 6) STEP(w7, kb + 7)
    }
    #undef STEP

    const v4f z4 = {0.f, 0.f, 0.f, 0.f};
    const v4f r00 = __builtin_elementwise_max(p00, z4);
    const v4f r01 = __builtin_elementwise_max(p01, z4);
    const v4f r10 = __builtin_elementwise_max(p10, z4);
    const v4f r11 = __builtin_elementwise_max(p11, z4);
    const v4f rs = (r00 + r01) + (r10 + r11);
    atomicAdd(&Slds[4*l + 0], rs.x);
    atomicAdd(&Slds[4*l + 1], rs.y);
    atomicAdd(&Slds[4*l + 2], rs.z);
    atomicAdd(&Slds[4*l + 3], rs.w);
    __syncthreads();
    if (t < 256) atomicAdd(&S[b * 256 + t], Slds[t]);
    asm volatile("s_waitcnt vmcnt(0)" ::: "memory");  // S atomics done before cnt
    __syncthreads();
    if (t == 0) {
        int old = atomicAdd(&cnt[b], 1);
        finflag = (old == 31);
    }
    __syncthreads();
    if (!finflag) return;

    // ===== tiny epilogue (one block per b): ricci_dir via Wp, then MLPs =====
    float* fs   = wr1c;          // 256
    float* rdp  = wr1c + 256;    // 512
    float* pl   = wr1c + 768;    // 32
    float* fin  = wr1c + 800;    // 64
    float* hf   = wr1c + 864;    // 128
    float* npos = wr1c + 992;    // 32
    float* hh   = wr1c + 1024;   // 128

    if (t < 256) fs[t] = atomicAdd(&S[b * 256 + t], 0.f) * (1.f / 1024.f);
    if (t < M) pl[t] = points[b * M + t];
    __syncthreads();
    {
        const int ii = t & 31, ch = t >> 5;   // 16 chunks x 16 u's
        float part = 0.f;
        #pragma unroll
        for (int uu = 0; uu < 16; ++uu) {
            const int u = ch * 16 + uu;
            part = fmaf(fs[u], Wp[u * 1024 + b * 32 + ii], part);
        }
        rdp[t] = part;
    }
    __syncthreads();
    if (t < M) {
        float a = c2[b * 32 + t];
        #pragma unroll
        for (int ch = 0; ch < 16; ++ch) a += rdp[ch * 32 + t];
        fin[t] = pl[t];
        fin[M + t] = a;
    }
    __syncthreads();
    if (t < H) {
        float acc = bf1[t];
        #pragma unroll
        for (int m = 0; m < 2 * M; ++m) acc = fmaf(fin[m], Wf1[m * H + t], acc);
        hf[t] = fmaxf(acc, 0.f);
    }
    __syncthreads();
    if (t < M) {
        float acc = bf2[t];
        #pragma unroll
        for (int u = 0; u < H; ++u) acc = fmaf(hf[u], Wf2[u * M + t], acc);
        npos[t] = pl[t] + acc;
    }
    __syncthreads();
    if (t < H) {
        float acc = bh1[t];
        #pragma unroll
        for (int m = 0; m < M; ++m) acc = fmaf(npos[m], Wh1[m * H + t], acc);
        hh[t] = tanhf(acc);
    }
    __syncthreads();
    if (t < 2 * M) {
        float acc = bh2[t];
        #pragma unroll
        for (int u = 0; u < H; ++u) acc = fmaf(hh[u], Wh2[u * (2 * M) + t], acc);
        out[b * (2 * M) + t] = acc;
    }
}

extern "C" void kernel_launch(void* const* d_in, const int* in_sizes, int n_in,
                              void* d_out, int out_size, void* d_ws, size_t ws_size,
                              hipStream_t stream)
{
    const float* points = (const float*)d_in[0];
    const float* Wm1 = (const float*)d_in[1];
    const float* bm1 = (const float*)d_in[2];
    const float* Wm2 = (const float*)d_in[3];
    const float* bm2 = (const float*)d_in[4];
    const float* Wc1 = (const float*)d_in[5];
    const float* bc1 = (const float*)d_in[6];
    const float* Wc2 = (const float*)d_in[7];
    const float* bc2 = (const float*)d_in[8];
    const float* Wr1 = (const float*)d_in[9];
    const float* br1 = (const float*)d_in[10];
    const float* Wr2 = (const float*)d_in[11];
    const float* br2 = (const float*)d_in[12];
    const float* Wf1 = (const float*)d_in[13];
    const float* bf1 = (const float*)d_in[14];
    const float* Wf2 = (const float*)d_in[15];
    const float* bf2 = (const float*)d_in[16];
    const float* Wh1 = (const float*)d_in[17];
    const float* bh1 = (const float*)d_in[18];
    const float* Wh2 = (const float*)d_in[19];
    const float* bh2 = (const float*)d_in[20];
    float* out = (float*)d_out;

    float* ws     = (float*)d_ws;
    float* metric = ws;                    // 32768
    float* mj     = ws + 32768;            // 262144
    float* S      = ws + 294912;           // 8192
    float* bc1s   = ws + 303104;           // 128
    float* Kc     = ws + 303232;           // 1
    int*   cnt    = (int*)(ws + 303236);   // 32 ints
    float* Wp     = ws + 303268;           // 262144
    float* c2     = ws + 565412;           // 1024

    k_prep<<<289, 256, 0, stream>>>(points, Wm1, bm1, Wm2, bm2, Wr1, bc1, Wc2,
                                    bc2, Wr2, br2, metric, mj, S, bc1s, Kc,
                                    cnt, Wp, c2);
    k_main<<<B * M, 512, 0, stream>>>(points, metric, mj, Wc1, Wc2, bc1s, Kc,
                                      Wr1, br1, S, cnt,
                                      Wp, c2, Wf1, bf1, Wf2, bf2,
                                      Wh1, bh1, Wh2, bh2, out);
}

// Round 14
// 59.372 us; speedup vs baseline: 1.3337x; 1.0177x over previous
//
#include <hip/hip_runtime.h>

#define B 32
#define M 32
#define H 128
#define EPS 1e-6f
#define TSCALE 2.8853900817779268f   // 2*log2(e)

typedef float v2f __attribute__((ext_vector_type(2)));
typedef float v4f __attribute__((ext_vector_type(4)));

static __device__ __forceinline__ v2f splat2(float x) { return (v2f){x, x}; }
static __device__ __forceinline__ v4f splat4(float x) { return (v4f){x, x, x, x}; }
static __device__ __forceinline__ v2f fma2(v2f a, v2f b, v2f c) {
    return __builtin_elementwise_fma(a, b, c);
}
static __device__ __forceinline__ v4f fma4(v4f a, v4f b, v4f c) {
    return __builtin_elementwise_fma(a, b, c);
}

// ---------------- workspace layout (floats) ----------------
// metric  @ 0      : 32768
// mj      @ 32768  : 262144  mj[b][j][d]  = metric[b,j,:] @ Wr1[64:96]
// S       @ 294912 : 8192
// bc1s    @ 303104 : 128     bc1 * 2log2(e)
// Kc      @ 303232 : 1       sum(Wc2) + bc2
// cnt     @ 303236 : 32 ints
// Wp      @ 303268 : 262144  Wp[u][b][i] = sum_j sym(Wr2)[u,i,j] * p[b,j]
// c2      @ 565412 : 1024    c2[b][i]    = sum_j sym(br2)[i,j] * p[b,j]
// bmi_pre @ 566436 : 262144  bmi_pre[b][i][d] = br1 + p@Wr1[0:32] + metric_i@Wr1[32:64]

#define FMA4(P, s, W) \
    P.x = fmaf((s), (W).x, P.x); P.y = fmaf((s), (W).y, P.y); \
    P.z = fmaf((s), (W).z, P.z); P.w = fmaf((s), (W).w, P.w);

// Kernel 1, grid 289: blocks 0-31 = per-b prep (metric, mj, bmi_pre, zero
// S/cnt, chris constants); blocks 32-287 = Wp row u = blk-32; block 288 = c2.
__global__ __launch_bounds__(256) void k_prep(
    const float* __restrict__ points, const float* __restrict__ Wm1,
    const float* __restrict__ bm1, const float* __restrict__ Wm2,
    const float* __restrict__ bm2, const float* __restrict__ Wr1,
    const float* __restrict__ br1, const float* __restrict__ bc1,
    const float* __restrict__ Wc2, const float* __restrict__ bc2,
    const float* __restrict__ Wr2, const float* __restrict__ br2,
    float* __restrict__ metric, float* __restrict__ mj,
    float* __restrict__ S, float* __restrict__ bc1s, float* __restrict__ Kc,
    int* __restrict__ cnt, float* __restrict__ Wp, float* __restrict__ c2,
    float* __restrict__ bmi_pre)
{
    __shared__ float sbuf[3392];
    const int role = blockIdx.x, t = threadIdx.x;

    if (role >= B) {
        // ---- Wp / c2 path: symmetrize one Wr2 row, contract with points ----
        const int u = role - B;                 // 0..255 = Wr2 row, 256 = br2
        float* row    = sbuf;                   // [32][33] = 1056
        float* rowsym = sbuf + 1056;            // [32][36] = 1152
        float* ps     = sbuf + 2208;            // [32][36] = 1152
        const float* src = (u < 256) ? (Wr2 + u * 1024) : br2;
        #pragma unroll
        for (int r = 0; r < 4; ++r) {
            const int d = t + 256 * r;
            row[(d >> 5) * 33 + (d & 31)] = src[d];
            ps[(d >> 5) * 36 + (d & 31)]  = points[d];
        }
        __syncthreads();
        #pragma unroll
        for (int r = 0; r < 4; ++r) {
            const int d = t + 256 * r, ii = d >> 5, jj = d & 31;
            rowsym[ii * 36 + jj] = 0.5f * (row[ii * 33 + jj] + row[jj * 33 + ii]);
        }
        __syncthreads();
        const int b = t >> 3, i0 = (t & 7) * 4;
        const float4* rs4 = (const float4*)rowsym;      // row stride 9 float4
        const float4* p4  = (const float4*)(ps + b * 36);
        float4 o; o.x = o.y = o.z = o.w = 0.f;
        #pragma unroll
        for (int m = 0; m < 8; ++m) {
            const float4 pv = p4[m];
            const float4 r0 = rs4[(i0 + 0) * 9 + m];
            const float4 r1 = rs4[(i0 + 1) * 9 + m];
            const float4 r2 = rs4[(i0 + 2) * 9 + m];
            const float4 r3 = rs4[(i0 + 3) * 9 + m];
            o.x = fmaf(pv.x, r0.x, fmaf(pv.y, r0.y, fmaf(pv.z, r0.z, fmaf(pv.w, r0.w, o.x))));
            o.y = fmaf(pv.x, r1.x, fmaf(pv.y, r1.y, fmaf(pv.z, r1.z, fmaf(pv.w, r1.w, o.y))));
            o.z = fmaf(pv.x, r2.x, fmaf(pv.y, r2.y, fmaf(pv.z, r2.z, fmaf(pv.w, r2.w, o.z))));
            o.w = fmaf(pv.x, r3.x, fmaf(pv.y, r3.y, fmaf(pv.z, r3.z, fmaf(pv.w, r3.w, o.w))));
        }
        if (u < 256) ((float4*)(Wp + u * 1024 + b * 32))[t & 7] = o;
        else         ((float4*)(c2 + b * 32))[t & 7] = o;
        return;
    }

    // ---- per-b prep path ----
    const int b = role;
    float* p     = sbuf;           // 32
    float* h     = sbuf + 32;      // 128
    float* comps = sbuf + 160;     // [32][33] = 1056
    float* msym  = sbuf + 1216;    // 1024
    if (t < M) p[t] = points[b * M + t];
    __syncthreads();
    if (t < H) {
        float acc = bm1[t];
        #pragma unroll
        for (int m = 0; m < M; ++m) acc = fmaf(p[m], Wm1[m * H + t], acc);
        h[t] = fmaxf(acc, 0.f);
    }
    __syncthreads();
    // comps: thread t owns 4 consecutive dims; b128 Wm2 loads, h broadcasts.
    {
        float4 acc = ((const float4*)bm2)[t];
        const float4* Wm2_4 = (const float4*)Wm2;     // row stride 256 float4
        const float4* h4 = (const float4*)h;
        #pragma unroll 2
        for (int u4 = 0; u4 < 32; ++u4) {
            const float4 hv = h4[u4];
            const float4 w0 = Wm2_4[(u4 * 4 + 0) * 256 + t];
            const float4 w1 = Wm2_4[(u4 * 4 + 1) * 256 + t];
            const float4 w2 = Wm2_4[(u4 * 4 + 2) * 256 + t];
            const float4 w3 = Wm2_4[(u4 * 4 + 3) * 256 + t];
            FMA4(acc, hv.x, w0); FMA4(acc, hv.y, w1);
            FMA4(acc, hv.z, w2); FMA4(acc, hv.w, w3);
        }
        const int row = t >> 3, col0 = (t & 7) * 4;
        comps[row * 33 + col0 + 0] = acc.x;
        comps[row * 33 + col0 + 1] = acc.y;
        comps[row * 33 + col0 + 2] = acc.z;
        comps[row * 33 + col0 + 3] = acc.w;
    }
    __syncthreads();
    {
        const int row = t >> 3, col0 = (t & 7) * 4;
        #pragma unroll
        for (int c = 0; c < 4; ++c) {
            const int d = 4 * t + c, ii = row, jj = col0 + c;
            float v = 0.5f * (comps[ii * 33 + jj] + comps[jj * 33 + ii]) + (ii == jj ? EPS : 0.f);
            metric[b * M * M + d] = v;
            msym[d] = v;
        }
    }
    S[b * 256 + t] = 0.f;
    if (t == 0) cnt[b] = 0;
    __syncthreads();
    // mj[b][x][t] and bmi_pre[b][x][t] in one pass (wreg = Wr1[64:96],
    // wreg2 = Wr1[32:64]); pbr = br1 + points@Wr1[0:32].
    float wreg[M], wreg2[M];
    #pragma unroll
    for (int m = 0; m < M; ++m) {
        wreg[m]  = Wr1[(64 + m) * 256 + t];
        wreg2[m] = Wr1[(32 + m) * 256 + t];
    }
    float pbr = br1[t];
    #pragma unroll
    for (int m = 0; m < M; ++m) pbr = fmaf(p[m], Wr1[m * 256 + t], pbr);
    const float4* msym4 = (const float4*)msym;   // broadcast reads
    for (int x = 0; x < M; ++x) {
        float acc = 0.f, acc2 = pbr;
        #pragma unroll
        for (int mq = 0; mq < 8; ++mq) {
            float4 mv = msym4[x * 8 + mq];
            acc  = fmaf(mv.x, wreg[4 * mq + 0], acc);
            acc  = fmaf(mv.y, wreg[4 * mq + 1], acc);
            acc  = fmaf(mv.z, wreg[4 * mq + 2], acc);
            acc  = fmaf(mv.w, wreg[4 * mq + 3], acc);
            acc2 = fmaf(mv.x, wreg2[4 * mq + 0], acc2);
            acc2 = fmaf(mv.y, wreg2[4 * mq + 1], acc2);
            acc2 = fmaf(mv.z, wreg2[4 * mq + 2], acc2);
            acc2 = fmaf(mv.w, wreg2[4 * mq + 3], acc2);
        }
        mj[(b * M + x) * 256 + t] = acc;
        bmi_pre[(b * M + x) * 256 + t] = acc2;
    }
    if (b == 0) {
        if (t < H) bc1s[t] = bc1[t] * TSCALE;
        if (t == 0) {
            float s = bc2[0];
            for (int u = 0; u < H; ++u) s += Wc2[u];
            Kc[0] = s;
        }
    }
}

// Kernel 2: per block (b,i): christoffel MLP + ricci layer-1 + reduce into
// S[b]; 32nd finisher per b runs the tiny Wp epilogue. 512 threads, 8 waves.
// No serial prologue: metric read per-lane from L2; bmi precomputed; wr1c
// staged global->reg at start, reg->LDS after chris (T14 split) — ONE
// barrier before ricci. b = blk&31: same-b blocks share an XCD L2.
__global__ __launch_bounds__(512) void k_main(
    const float* __restrict__ points, const float* __restrict__ metric,
    const float* __restrict__ mj, const float* __restrict__ bmi_pre,
    const float* __restrict__ Wc1, const float* __restrict__ Wc2,
    const float* __restrict__ bc1s, const float* __restrict__ Kc,
    const float* __restrict__ Wr1, float* __restrict__ S,
    int* __restrict__ cnt,
    const float* __restrict__ Wp, const float* __restrict__ c2,
    const float* __restrict__ Wf1, const float* __restrict__ bf1,
    const float* __restrict__ Wf2, const float* __restrict__ bf2,
    const float* __restrict__ Wh1, const float* __restrict__ bh1,
    const float* __restrict__ Wh2, const float* __restrict__ bh2,
    float* __restrict__ out)
{
    const int blk = blockIdx.x;
    const int b = blk & 31, i = blk >> 5;
    const int t = threadIdx.x;
    const int w = t >> 6, l = t & 63;
    const int ph = l >> 5, k = l & 31;

    __shared__ float wr1c[M * 256];   // 32 KB (epilogue scratch later)
    __shared__ float chlds[8 * 128];  // per-wave chris, packed [k][slot]
    __shared__ float Slds[256];
    __shared__ int finflag;

    // ---- early loads, in consumption order (vmcnt is FIFO) ----
    // (1) metric values for chris:
    const float* mb = metric + b * 1024;
    const int j0 = 2 * w + ph, j1 = 16 + 2 * w + ph;
    const float gki  = mb[i * M + k] * TSCALE;
    const v2f gijv = {mb[i * M + j0] * TSCALE, mb[i * M + j1] * TSCALE};
    const v2f gjkv = {mb[j0 * M + k] * TSCALE, mb[j1 * M + k] * TSCALE};
    // (2) accumulator init (mj + bmi), consumed at ricci start:
    const v4f* mj4 = (const v4f*)(mj + b * M * 256);
    const int jb = w * 2;
    v4f p00 = mj4[(jb + 0) * 64 + l];
    v4f p01 = mj4[(jb + 1) * 64 + l];
    v4f p10 = mj4[(jb + 16) * 64 + l];
    v4f p11 = mj4[(jb + 17) * 64 + l];
    const v4f bmiv = ((const v4f*)(bmi_pre + (b * M + i) * 256))[l];
    // (3) wr1c tile global->reg (LDS write deferred past chris):
    v4f wst0, wst1, wst2, wst3;
    {
        const v4f* src = (const v4f*)(Wr1 + 96 * 256);
        wst0 = src[t];       wst1 = src[t + 512];
        wst2 = src[t + 1024]; wst3 = src[t + 1536];
    }
    if (t < 256) Slds[t] = 0.f;

    // ---- christoffel: (j0,j1) pair as v2f -> v_pk_fma_f32 ----
    v2f acc2 = {0.f, 0.f};
    #pragma unroll 8
    for (int u = 0; u < H; ++u) {
        const float tc = fmaf(gki, Wc1[2 * H + u], bc1s[u]);
        v2f pre = fma2(gijv, splat2(Wc1[u]), fma2(gjkv, splat2(Wc1[H + u]), splat2(tc)));
        v2f e = {__builtin_amdgcn_exp2f(pre.x), __builtin_amdgcn_exp2f(pre.y)};
        e += (v2f){1.f, 1.f};
        const v2f r = {__builtin_amdgcn_rcpf(e.x), __builtin_amdgcn_rcpf(e.y)};
        acc2 = fma2(r, splat2(Wc2[u]), acc2);
    }
    const float KcV = Kc[0];
    // per-wave scratch, packed [k][slot]; slot {0:j0|ph=0, 1:j0|ph=1,
    // 2:j1|ph=0, 3:j1|ph=1} -> one broadcast b128 per k in ricci.
    chlds[w * 128 + k * 4 + ph]     = fmaf(-2.f, acc2.x, KcV);
    chlds[w * 128 + k * 4 + 2 + ph] = fmaf(-2.f, acc2.y, KcV);

    // ---- deferred wr1c LDS write (loads had ~chris-length to land) ----
    {
        v4f* dst = (v4f*)wr1c;
        dst[t] = wst0;        dst[t + 512] = wst1;
        dst[t + 1024] = wst2; dst[t + 1536] = wst3;
    }
    __syncthreads();   // wr1c ready (chlds is wave-private, needs no barrier)

    // ---- ricci layer-1: lane l owns dims 4l..4l+3 for the wave's 4 j's ----
    const v4f* wr1c4 = (const v4f*)wr1c;
    const v4f* ch4 = (const v4f*)(chlds + w * 128);   // broadcast reads
    p00 += bmiv; p01 += bmiv; p10 += bmiv; p11 += bmiv;

    #define STEP(W, kk) { \
        const v4f s = ch4[kk]; \
        p00 = fma4(splat4(s.x), W, p00); p01 = fma4(splat4(s.y), W, p01); \
        p10 = fma4(splat4(s.z), W, p10); p11 = fma4(splat4(s.w), W, p11); }

    #pragma unroll
    for (int kc = 0; kc < 4; ++kc) {
        const int kb = kc * 8;
        const v4f w0 = wr1c4[(kb + 0) * 64 + l];
        const v4f w1 = wr1c4[(kb + 1) * 64 + l];
        const v4f w2 = wr1c4[(kb + 2) * 64 + l];
        const v4f w3 = wr1c4[(kb + 3) * 64 + l];
        const v4f w4 = wr1c4[(kb + 4) * 64 + l];
        const v4f w5 = wr1c4[(kb + 5) * 64 + l];
        const v4f w6 = wr1c4[(kb + 6) * 64 + l];
        const v4f w7 = wr1c4[(kb + 7) * 64 + l];
        STEP(w0, kb + 0) STEP(w1, kb + 1) STEP(w2, kb + 2) STEP(w3, kb + 3)
        STEP(w4, kb + 4) STEP(w5, kb + 5) STEP(w6, kb + 6) STEP(w7, kb + 7)
    }
    #undef STEP

    const v4f z4 = {0.f, 0.f, 0.f, 0.f};
    const v4f r00 = __builtin_elementwise_max(p00, z4);
    const v4f r01 = __builtin_elementwise_max(p01, z4);
    const v4f r10 = __builtin_elementwise_max(p10, z4);
    const v4f r11 = __builtin_elementwise_max(p11, z4);
    const v4f rs = (r00 + r01) + (r10 + r11);
    atomicAdd(&Slds[4*l + 0], rs.x);
    atomicAdd(&Slds[4*l + 1], rs.y);
    atomicAdd(&Slds[4*l + 2], rs.z);
    atomicAdd(&Slds[4*l + 3], rs.w);
    __syncthreads();
    if (t < 256) atomicAdd(&S[b * 256 + t], Slds[t]);
    asm volatile("s_waitcnt vmcnt(0)" ::: "memory");  // S atomics done before cnt
    __syncthreads();
    if (t == 0) {
        int old = atomicAdd(&cnt[b], 1);
        finflag = (old == 31);
    }
    __syncthreads();
    if (!finflag) return;

    // ===== tiny epilogue (one block per b): ricci_dir via Wp, then MLPs =====
    float* fs   = wr1c;          // 256
    float* rdp  = wr1c + 256;    // 512
    float* pl   = wr1c + 768;    // 32
    float* fin  = wr1c + 800;    // 64
    float* hf   = wr1c + 864;    // 128
    float* npos = wr1c + 992;    // 32
    float* hh   = wr1c + 1024;   // 128

    if (t < 256) fs[t] = atomicAdd(&S[b * 256 + t], 0.f) * (1.f / 1024.f);
    if (t < M) pl[t] = points[b * M + t];
    __syncthreads();
    {
        const int ii = t & 31, ch = t >> 5;   // 16 chunks x 16 u's
        float part = 0.f;
        #pragma unroll
        for (int uu = 0; uu < 16; ++uu) {
            const int u = ch * 16 + uu;
            part = fmaf(fs[u], Wp[u * 1024 + b * 32 + ii], part);
        }
        rdp[t] = part;
    }
    __syncthreads();
    if (t < M) {
        float a = c2[b * 32 + t];
        #pragma unroll
        for (int ch = 0; ch < 16; ++ch) a += rdp[ch * 32 + t];
        fin[t] = pl[t];
        fin[M + t] = a;
    }
    __syncthreads();
    if (t < H) {
        float acc = bf1[t];
        #pragma unroll
        for (int m = 0; m < 2 * M; ++m) acc = fmaf(fin[m], Wf1[m * H + t], acc);
        hf[t] = fmaxf(acc, 0.f);
    }
    __syncthreads();
    if (t < M) {
        float acc = bf2[t];
        #pragma unroll
        for (int u = 0; u < H; ++u) acc = fmaf(hf[u], Wf2[u * M + t], acc);
        npos[t] = pl[t] + acc;
    }
    __syncthreads();
    if (t < H) {
        float acc = bh1[t];
        #pragma unroll
        for (int m = 0; m < M; ++m) acc = fmaf(npos[m], Wh1[m * H + t], acc);
        hh[t] = tanhf(acc);
    }
    __syncthreads();
    if (t < 2 * M) {
        float acc = bh2[t];
        #pragma unroll
        for (int u = 0; u < H; ++u) acc = fmaf(hh[u], Wh2[u * (2 * M) + t], acc);
        out[b * (2 * M) + t] = acc;
    }
}

extern "C" void kernel_launch(void* const* d_in, const int* in_sizes, int n_in,
                              void* d_out, int out_size, void* d_ws, size_t ws_size,
                              hipStream_t stream)
{
    const float* points = (const float*)d_in[0];
    const float* Wm1 = (const float*)d_in[1];
    const float* bm1 = (const float*)d_in[2];
    const float* Wm2 = (const float*)d_in[3];
    const float* bm2 = (const float*)d_in[4];
    const float* Wc1 = (const float*)d_in[5];
    const float* bc1 = (const float*)d_in[6];
    const float* Wc2 = (const float*)d_in[7];
    const float* bc2 = (const float*)d_in[8];
    const float* Wr1 = (const float*)d_in[9];
    const float* br1 = (const float*)d_in[10];
    const float* Wr2 = (const float*)d_in[11];
    const float* br2 = (const float*)d_in[12];
    const float* Wf1 = (const float*)d_in[13];
    const float* bf1 = (const float*)d_in[14];
    const float* Wf2 = (const float*)d_in[15];
    const float* bf2 = (const float*)d_in[16];
    const float* Wh1 = (const float*)d_in[17];
    const float* bh1 = (const float*)d_in[18];
    const float* Wh2 = (const float*)d_in[19];
    const float* bh2 = (const float*)d_in[20];
    float* out = (float*)d_out;

    float* ws      = (float*)d_ws;
    float* metric  = ws;                    // 32768
    float* mj      = ws + 32768;            // 262144
    float* S       = ws + 294912;           // 8192
    float* bc1s    = ws + 303104;           // 128
    float* Kc      = ws + 303232;           // 1
    int*   cnt     = (int*)(ws + 303236);   // 32 ints
    float* Wp      = ws + 303268;           // 262144
    float* c2      = ws + 565412;           // 1024
    float* bmi_pre = ws + 566436;           // 262144

    k_prep<<<289, 256, 0, stream>>>(points, Wm1, bm1, Wm2, bm2, Wr1, br1, bc1,
                                    Wc2, bc2, Wr2, br2, metric, mj, S, bc1s,
                                    Kc, cnt, Wp, c2, bmi_pre);
    k_main<<<B * M, 512, 0, stream>>>(points, metric, mj, bmi_pre, Wc1, Wc2,
                                      bc1s, Kc, Wr1, S, cnt,
                                      Wp, c2, Wf1, bf1, Wf2, bf2,
                                      Wh1, bh1, Wh2, bh2, out);
}

// Round 15
// 57.757 us; speedup vs baseline: 1.3709x; 1.0280x over previous
//
#include <hip/hip_runtime.h>

#define B 32
#define M 32
#define H 128
#define EPS 1e-6f
#define TSCALE 2.8853900817779268f   // 2*log2(e)

typedef float v2f __attribute__((ext_vector_type(2)));
typedef float v4f __attribute__((ext_vector_type(4)));

static __device__ __forceinline__ v2f splat2(float x) { return (v2f){x, x}; }
static __device__ __forceinline__ v4f splat4(float x) { return (v4f){x, x, x, x}; }
static __device__ __forceinline__ v2f fma2(v2f a, v2f b, v2f c) {
    return __builtin_elementwise_fma(a, b, c);
}
static __device__ __forceinline__ v4f fma4(v4f a, v4f b, v4f c) {
    return __builtin_elementwise_fma(a, b, c);
}

// ---------------- workspace layout (floats) ----------------
// metric  @ 0      : 32768
// mj      @ 32768  : 262144  mj[b][j][d]  = metric[b,j,:] @ Wr1[64:96]
// S       @ 294912 : 8192
// bc1s    @ 303104 : 128     bc1 * 2log2(e)
// Kc      @ 303232 : 1       sum(Wc2) + bc2
// cnt     @ 303236 : 32 ints
// Wp      @ 303268 : 262144  Wp[u][b][i] = sum_j sym(Wr2)[u,i,j] * p[b,j]
// c2      @ 565412 : 1024    c2[b][i]    = sum_j sym(br2)[i,j] * p[b,j]
// bmi_pre @ 566436 : 262144  bmi_pre[b][i][d] = br1 + p@Wr1[0:32] + metric_i@Wr1[32:64]

#define FMA4(P, s, W) \
    P.x = fmaf((s), (W).x, P.x); P.y = fmaf((s), (W).y, P.y); \
    P.z = fmaf((s), (W).z, P.z); P.w = fmaf((s), (W).w, P.w);

// Kernel 1, grid 289: blocks 0-31 = per-b prep (metric, mj, bmi_pre, zero
// S/cnt, chris constants); blocks 32-287 = Wp row u = blk-32; block 288 = c2.
__global__ __launch_bounds__(256) void k_prep(
    const float* __restrict__ points, const float* __restrict__ Wm1,
    const float* __restrict__ bm1, const float* __restrict__ Wm2,
    const float* __restrict__ bm2, const float* __restrict__ Wr1,
    const float* __restrict__ br1, const float* __restrict__ bc1,
    const float* __restrict__ Wc2, const float* __restrict__ bc2,
    const float* __restrict__ Wr2, const float* __restrict__ br2,
    float* __restrict__ metric, float* __restrict__ mj,
    float* __restrict__ S, float* __restrict__ bc1s, float* __restrict__ Kc,
    int* __restrict__ cnt, float* __restrict__ Wp, float* __restrict__ c2,
    float* __restrict__ bmi_pre)
{
    __shared__ float sbuf[3392];
    const int role = blockIdx.x, t = threadIdx.x;

    if (role >= B) {
        // ---- Wp / c2 path: symmetrize one Wr2 row, contract with points ----
        const int u = role - B;                 // 0..255 = Wr2 row, 256 = br2
        float* row    = sbuf;                   // [32][33] = 1056
        float* rowsym = sbuf + 1056;            // [32][36] = 1152
        float* ps     = sbuf + 2208;            // [32][36] = 1152
        const float* src = (u < 256) ? (Wr2 + u * 1024) : br2;
        #pragma unroll
        for (int r = 0; r < 4; ++r) {
            const int d = t + 256 * r;
            row[(d >> 5) * 33 + (d & 31)] = src[d];
            ps[(d >> 5) * 36 + (d & 31)]  = points[d];
        }
        __syncthreads();
        #pragma unroll
        for (int r = 0; r < 4; ++r) {
            const int d = t + 256 * r, ii = d >> 5, jj = d & 31;
            rowsym[ii * 36 + jj] = 0.5f * (row[ii * 33 + jj] + row[jj * 33 + ii]);
        }
        __syncthreads();
        const int b = t >> 3, i0 = (t & 7) * 4;
        const float4* rs4 = (const float4*)rowsym;      // row stride 9 float4
        const float4* p4  = (const float4*)(ps + b * 36);
        float4 o; o.x = o.y = o.z = o.w = 0.f;
        #pragma unroll
        for (int m = 0; m < 8; ++m) {
            const float4 pv = p4[m];
            const float4 r0 = rs4[(i0 + 0) * 9 + m];
            const float4 r1 = rs4[(i0 + 1) * 9 + m];
            const float4 r2 = rs4[(i0 + 2) * 9 + m];
            const float4 r3 = rs4[(i0 + 3) * 9 + m];
            o.x = fmaf(pv.x, r0.x, fmaf(pv.y, r0.y, fmaf(pv.z, r0.z, fmaf(pv.w, r0.w, o.x))));
            o.y = fmaf(pv.x, r1.x, fmaf(pv.y, r1.y, fmaf(pv.z, r1.z, fmaf(pv.w, r1.w, o.y))));
            o.z = fmaf(pv.x, r2.x, fmaf(pv.y, r2.y, fmaf(pv.z, r2.z, fmaf(pv.w, r2.w, o.z))));
            o.w = fmaf(pv.x, r3.x, fmaf(pv.y, r3.y, fmaf(pv.z, r3.z, fmaf(pv.w, r3.w, o.w))));
        }
        if (u < 256) ((float4*)(Wp + u * 1024 + b * 32))[t & 7] = o;
        else         ((float4*)(c2 + b * 32))[t & 7] = o;
        return;
    }

    // ---- per-b prep path ----
    const int b = role;
    float* p     = sbuf;           // 32
    float* h     = sbuf + 32;      // 128
    float* comps = sbuf + 160;     // [32][33] = 1056
    float* msym  = sbuf + 1216;    // 1024
    if (t < M) p[t] = points[b * M + t];
    __syncthreads();
    if (t < H) {
        float acc = bm1[t];
        #pragma unroll
        for (int m = 0; m < M; ++m) acc = fmaf(p[m], Wm1[m * H + t], acc);
        h[t] = fmaxf(acc, 0.f);
    }
    __syncthreads();
    // comps: thread t owns 4 consecutive dims; b128 Wm2 loads, h broadcasts.
    {
        float4 acc = ((const float4*)bm2)[t];
        const float4* Wm2_4 = (const float4*)Wm2;     // row stride 256 float4
        const float4* h4 = (const float4*)h;
        #pragma unroll 2
        for (int u4 = 0; u4 < 32; ++u4) {
            const float4 hv = h4[u4];
            const float4 w0 = Wm2_4[(u4 * 4 + 0) * 256 + t];
            const float4 w1 = Wm2_4[(u4 * 4 + 1) * 256 + t];
            const float4 w2 = Wm2_4[(u4 * 4 + 2) * 256 + t];
            const float4 w3 = Wm2_4[(u4 * 4 + 3) * 256 + t];
            FMA4(acc, hv.x, w0); FMA4(acc, hv.y, w1);
            FMA4(acc, hv.z, w2); FMA4(acc, hv.w, w3);
        }
        const int row = t >> 3, col0 = (t & 7) * 4;
        comps[row * 33 + col0 + 0] = acc.x;
        comps[row * 33 + col0 + 1] = acc.y;
        comps[row * 33 + col0 + 2] = acc.z;
        comps[row * 33 + col0 + 3] = acc.w;
    }
    __syncthreads();
    {
        const int row = t >> 3, col0 = (t & 7) * 4;
        #pragma unroll
        for (int c = 0; c < 4; ++c) {
            const int d = 4 * t + c, ii = row, jj = col0 + c;
            float v = 0.5f * (comps[ii * 33 + jj] + comps[jj * 33 + ii]) + (ii == jj ? EPS : 0.f);
            metric[b * M * M + d] = v;
            msym[d] = v;
        }
    }
    S[b * 256 + t] = 0.f;
    if (t == 0) cnt[b] = 0;
    __syncthreads();
    // mj[b][x][t] and bmi_pre[b][x][t] in one pass (wreg = Wr1[64:96],
    // wreg2 = Wr1[32:64]); pbr = br1 + points@Wr1[0:32].
    float wreg[M], wreg2[M];
    #pragma unroll
    for (int m = 0; m < M; ++m) {
        wreg[m]  = Wr1[(64 + m) * 256 + t];
        wreg2[m] = Wr1[(32 + m) * 256 + t];
    }
    float pbr = br1[t];
    #pragma unroll
    for (int m = 0; m < M; ++m) pbr = fmaf(p[m], Wr1[m * 256 + t], pbr);
    const float4* msym4 = (const float4*)msym;   // broadcast reads
    for (int x = 0; x < M; ++x) {
        float acc = 0.f, acc2 = pbr;
        #pragma unroll
        for (int mq = 0; mq < 8; ++mq) {
            float4 mv = msym4[x * 8 + mq];
            acc  = fmaf(mv.x, wreg[4 * mq + 0], acc);
            acc  = fmaf(mv.y, wreg[4 * mq + 1], acc);
            acc  = fmaf(mv.z, wreg[4 * mq + 2], acc);
            acc  = fmaf(mv.w, wreg[4 * mq + 3], acc);
            acc2 = fmaf(mv.x, wreg2[4 * mq + 0], acc2);
            acc2 = fmaf(mv.y, wreg2[4 * mq + 1], acc2);
            acc2 = fmaf(mv.z, wreg2[4 * mq + 2], acc2);
            acc2 = fmaf(mv.w, wreg2[4 * mq + 3], acc2);
        }
        mj[(b * M + x) * 256 + t] = acc;
        bmi_pre[(b * M + x) * 256 + t] = acc2;
    }
    if (b == 0) {
        if (t < H) bc1s[t] = bc1[t] * TSCALE;
        if (t == 0) {
            float s = bc2[0];
            for (int u = 0; u < H; ++u) s += Wc2[u];
            Kc[0] = s;
        }
    }
}

// Kernel 2: per block (b,i): christoffel MLP + ricci layer-1 + reduce into
// S[b]; 32nd finisher per b runs the tiny Wp epilogue. 512 threads, 8 waves.
// LDS cut 38.4K -> ~5.3K: ricci weights read DIRECTLY from global (32 KB
// tile is L1/L2-resident, shared by every wave on the CU). Cross-round
// evidence says ~39KB-LDS blocks only co-reside 1-2/CU (occupancy pinned
// 25-43% for 10 rounds); tiny-LDS blocks should hit the 32-wave cap.
__global__ __launch_bounds__(512) void k_main(
    const float* __restrict__ points, const float* __restrict__ metric,
    const float* __restrict__ mj, const float* __restrict__ bmi_pre,
    const float* __restrict__ Wc1, const float* __restrict__ Wc2,
    const float* __restrict__ bc1s, const float* __restrict__ Kc,
    const float* __restrict__ Wr1, float* __restrict__ S,
    int* __restrict__ cnt,
    const float* __restrict__ Wp, const float* __restrict__ c2,
    const float* __restrict__ Wf1, const float* __restrict__ bf1,
    const float* __restrict__ Wf2, const float* __restrict__ bf2,
    const float* __restrict__ Wh1, const float* __restrict__ bh1,
    const float* __restrict__ Wh2, const float* __restrict__ bh2,
    float* __restrict__ out)
{
    const int blk = blockIdx.x;
    const int b = blk & 31, i = blk >> 5;
    const int t = threadIdx.x;
    const int w = t >> 6, l = t & 63;
    const int ph = l >> 5, k = l & 31;

    __shared__ float chlds[8 * 128];  // per-wave chris, packed [k][slot] (4 KB)
    __shared__ float Slds[256];       // 1 KB
    __shared__ int finflag;

    // ---- early loads, in consumption order ----
    const float* mb = metric + b * 1024;
    const int j0 = 2 * w + ph, j1 = 16 + 2 * w + ph;
    const float gki  = mb[i * M + k] * TSCALE;
    const v2f gijv = {mb[i * M + j0] * TSCALE, mb[i * M + j1] * TSCALE};
    const v2f gjkv = {mb[j0 * M + k] * TSCALE, mb[j1 * M + k] * TSCALE};
    const v4f* mj4 = (const v4f*)(mj + b * M * 256);
    const int jb = w * 2;
    v4f p00 = mj4[(jb + 0) * 64 + l];
    v4f p01 = mj4[(jb + 1) * 64 + l];
    v4f p10 = mj4[(jb + 16) * 64 + l];
    v4f p11 = mj4[(jb + 17) * 64 + l];
    const v4f bmiv = ((const v4f*)(bmi_pre + (b * M + i) * 256))[l];
    if (t < 256) Slds[t] = 0.f;

    // ---- christoffel: (j0,j1) pair as v2f -> v_pk_fma_f32 ----
    v2f acc2 = {0.f, 0.f};
    #pragma unroll 8
    for (int u = 0; u < H; ++u) {
        const float tc = fmaf(gki, Wc1[2 * H + u], bc1s[u]);
        v2f pre = fma2(gijv, splat2(Wc1[u]), fma2(gjkv, splat2(Wc1[H + u]), splat2(tc)));
        v2f e = {__builtin_amdgcn_exp2f(pre.x), __builtin_amdgcn_exp2f(pre.y)};
        e += (v2f){1.f, 1.f};
        const v2f r = {__builtin_amdgcn_rcpf(e.x), __builtin_amdgcn_rcpf(e.y)};
        acc2 = fma2(r, splat2(Wc2[u]), acc2);
    }
    const float KcV = Kc[0];
    // per-wave scratch, packed [k][slot] -> one broadcast b128 per k in ricci.
    chlds[w * 128 + k * 4 + ph]     = fmaf(-2.f, acc2.x, KcV);
    chlds[w * 128 + k * 4 + 2 + ph] = fmaf(-2.f, acc2.y, KcV);
    // chlds is wave-private: intra-wave lgkmcnt ordering suffices, no barrier.

    // ---- ricci layer-1: weights streamed from global (L1/L2-hot tile) ----
    const v4f* wg = (const v4f*)(Wr1 + 96 * 256);
    const v4f* ch4 = (const v4f*)(chlds + w * 128);   // broadcast reads
    p00 += bmiv; p01 += bmiv; p10 += bmiv; p11 += bmiv;

    #define STEP(W, kk) { \
        const v4f s = ch4[kk]; \
        p00 = fma4(splat4(s.x), W, p00); p01 = fma4(splat4(s.y), W, p01); \
        p10 = fma4(splat4(s.z), W, p10); p11 = fma4(splat4(s.w), W, p11); }

    // 8 groups of 4: bounds live weight regs (~16 VGPR) while giving the
    // scheduler 4 independent loads to pipeline per group.
    #pragma unroll
    for (int kc = 0; kc < 8; ++kc) {
        const int kb = kc * 4;
        const v4f w0 = wg[(kb + 0) * 64 + l];
        const v4f w1 = wg[(kb + 1) * 64 + l];
        const v4f w2 = wg[(kb + 2) * 64 + l];
        const v4f w3 = wg[(kb + 3) * 64 + l];
        STEP(w0, kb + 0) STEP(w1, kb + 1) STEP(w2, kb + 2) STEP(w3, kb + 3)
    }
    #undef STEP

    const v4f z4 = {0.f, 0.f, 0.f, 0.f};
    const v4f r00 = __builtin_elementwise_max(p00, z4);
    const v4f r01 = __builtin_elementwise_max(p01, z4);
    const v4f r10 = __builtin_elementwise_max(p10, z4);
    const v4f r11 = __builtin_elementwise_max(p11, z4);
    const v4f rs = (r00 + r01) + (r10 + r11);
    atomicAdd(&Slds[4*l + 0], rs.x);
    atomicAdd(&Slds[4*l + 1], rs.y);
    atomicAdd(&Slds[4*l + 2], rs.z);
    atomicAdd(&Slds[4*l + 3], rs.w);
    __syncthreads();
    if (t < 256) atomicAdd(&S[b * 256 + t], Slds[t]);
    asm volatile("s_waitcnt vmcnt(0)" ::: "memory");  // S atomics done before cnt
    __syncthreads();
    if (t == 0) {
        int old = atomicAdd(&cnt[b], 1);
        finflag = (old == 31);
    }
    __syncthreads();
    if (!finflag) return;

    // ===== tiny epilogue (one block per b): ricci_dir via Wp, then MLPs =====
    // scratch mapped onto chlds (1024) + Slds (256): fs 0-255, rdp 256-767,
    // pl 768-799, fin 800-863, hf 864-991, npos: Slds[0:32], hh: Slds[32:160]
    float* fs   = chlds;
    float* rdp  = chlds + 256;
    float* pl   = chlds + 768;
    float* fin  = chlds + 800;
    float* hf   = chlds + 864;
    float* npos = Slds;
    float* hh   = Slds + 32;

    if (t < 256) fs[t] = atomicAdd(&S[b * 256 + t], 0.f) * (1.f / 1024.f);
    if (t < M) pl[t] = points[b * M + t];
    __syncthreads();
    {
        const int ii = t & 31, ch = t >> 5;   // 16 chunks x 16 u's
        float part = 0.f;
        #pragma unroll
        for (int uu = 0; uu < 16; ++uu) {
            const int u = ch * 16 + uu;
            part = fmaf(fs[u], Wp[u * 1024 + b * 32 + ii], part);
        }
        rdp[t] = part;
    }
    __syncthreads();
    if (t < M) {
        float a = c2[b * 32 + t];
        #pragma unroll
        for (int ch = 0; ch < 16; ++ch) a += rdp[ch * 32 + t];
        fin[t] = pl[t];
        fin[M + t] = a;
    }
    __syncthreads();
    if (t < H) {
        float acc = bf1[t];
        #pragma unroll
        for (int m = 0; m < 2 * M; ++m) acc = fmaf(fin[m], Wf1[m * H + t], acc);
        hf[t] = fmaxf(acc, 0.f);
    }
    __syncthreads();
    if (t < M) {
        float acc = bf2[t];
        #pragma unroll
        for (int u = 0; u < H; ++u) acc = fmaf(hf[u], Wf2[u * M + t], acc);
        npos[t] = pl[t] + acc;
    }
    __syncthreads();
    if (t < H) {
        float acc = bh1[t];
        #pragma unroll
        for (int m = 0; m < M; ++m) acc = fmaf(npos[m], Wh1[m * H + t], acc);
        hh[t] = tanhf(acc);
    }
    __syncthreads();
    if (t < 2 * M) {
        float acc = bh2[t];
        #pragma unroll
        for (int u = 0; u < H; ++u) acc = fmaf(hh[u], Wh2[u * (2 * M) + t], acc);
        out[b * (2 * M) + t] = acc;
    }
}

extern "C" void kernel_launch(void* const* d_in, const int* in_sizes, int n_in,
                              void* d_out, int out_size, void* d_ws, size_t ws_size,
                              hipStream_t stream)
{
    const float* points = (const float*)d_in[0];
    const float* Wm1 = (const float*)d_in[1];
    const float* bm1 = (const float*)d_in[2];
    const float* Wm2 = (const float*)d_in[3];
    const float* bm2 = (const float*)d_in[4];
    const float* Wc1 = (const float*)d_in[5];
    const float* bc1 = (const float*)d_in[6];
    const float* Wc2 = (const float*)d_in[7];
    const float* bc2 = (const float*)d_in[8];
    const float* Wr1 = (const float*)d_in[9];
    const float* br1 = (const float*)d_in[10];
    const float* Wr2 = (const float*)d_in[11];
    const float* br2 = (const float*)d_in[12];
    const float* Wf1 = (const float*)d_in[13];
    const float* bf1 = (const float*)d_in[14];
    const float* Wf2 = (const float*)d_in[15];
    const float* bf2 = (const float*)d_in[16];
    const float* Wh1 = (const float*)d_in[17];
    const float* bh1 = (const float*)d_in[18];
    const float* Wh2 = (const float*)d_in[19];
    const float* bh2 = (const float*)d_in[20];
    float* out = (float*)d_out;

    float* ws      = (float*)d_ws;
    float* metric  = ws;                    // 32768
    float* mj      = ws + 32768;            // 262144
    float* S       = ws + 294912;           // 8192
    float* bc1s    = ws + 303104;           // 128
    float* Kc      = ws + 303232;           // 1
    int*   cnt     = (int*)(ws + 303236);   // 32 ints
    float* Wp      = ws + 303268;           // 262144
    float* c2      = ws + 565412;           // 1024
    float* bmi_pre = ws + 566436;           // 262144

    k_prep<<<289, 256, 0, stream>>>(points, Wm1, bm1, Wm2, bm2, Wr1, br1, bc1,
                                    Wc2, bc2, Wr2, br2, metric, mj, S, bc1s,
                                    Kc, cnt, Wp, c2, bmi_pre);
    k_main<<<B * M, 512, 0, stream>>>(points, metric, mj, bmi_pre, Wc1, Wc2,
                                      bc1s, Kc, Wr1, S, cnt,
                                      Wp, c2, Wf1, bf1, Wf2, bf2,
                                      Wh1, bh1, Wh2, bh2, out);
}